// Round 10
// baseline (351.952 us; speedup 1.0000x reference)
//
#include <hip/hip_runtime.h>
#include <hip/hip_bf16.h>
#include <math.h>

// Problem dims (fixed by reference)
#define BB   256      // batch
#define LDE  64       // desc tokens len
#define NO   10240    // outer nodes
#define LO   32       // x tokens len
#define NM   81920    // mini nodes
#define LM   16       // mini tokens len
#define EO   81920    // outer edges
#define EM   327680   // mini edges
#define ED   128      // embed dim E
#define HIDD 256      // hidden
#define NH   8        // heads
#define DH   16       // head dim
#define VV   10000    // vocab

static inline int nblk(long long n, int b) { return (int)((n + b - 1) / b); }

typedef __attribute__((ext_vector_type(8))) short short8;
typedef __attribute__((ext_vector_type(4))) float f32x4;

// ---- fp32 <-> bf16 (RNE) helpers ----
static __device__ __forceinline__ unsigned short bf16_rne(float f) {
  unsigned u = __float_as_uint(f);
  return (unsigned short)((u + 0x7fffu + ((u >> 16) & 1u)) >> 16);
}
static __device__ __forceinline__ float bf16_to_f(unsigned short h) {
  return __uint_as_float(((unsigned)h) << 16);
}
static __device__ __forceinline__ float4 b4f(ushort4 h) {
  return make_float4(bf16_to_f(h.x), bf16_to_f(h.y), bf16_to_f(h.z), bf16_to_f(h.w));
}
static __device__ __forceinline__ ushort4 f4b(float4 v) {
  return make_ushort4(bf16_rne(v.x), bf16_rne(v.y), bf16_rne(v.z), bf16_rne(v.w));
}

// async global->LDS, 16B/lane. LDS dest must be wave-uniform base; global src per-lane.
static __device__ __forceinline__ void gl_lds16(const void* g, void* l) {
  __builtin_amdgcn_global_load_lds(
      (const __attribute__((address_space(1))) unsigned int*)g,
      (__attribute__((address_space(3))) unsigned int*)l, 16, 0, 0);
}

// ======================================================================
// Conversion kernel
// ======================================================================
struct ConvArgs {
  const float *Wq, *Wk, *Wv, *Ws, *W2, *W3;
  const float *bq, *bk, *bv, *bs;
  short8* frag;            // 16384 octets: [0,8192) QKVS, [8192,12288) W2, [12288,16384) W3
  float* bias512;
  const float* t1; unsigned short* o1;
  const float* t2; unsigned short* o2;
  int* hist;
};
#define TBLK (2 * VV * ED / 4 / 256)      // 2500 table blocks
#define ZBLK ((NM + NO) / 256)            // 360 hist-zero blocks
__global__ void __launch_bounds__(256)
conv_all_k(ConvArgs A) {
  int b = blockIdx.x;
  if (b < 32) {
    // merged QKVS frags, chunk-major: octet g in [0,8192)
    int g = b * 256 + threadIdx.x;
    int lane = g & 63, f = g >> 6;        // f = (ch<<5)|(kb<<3)|jl
    int jl = f & 7, kb = (f >> 3) & 3, ch = f >> 5;
    int cf = ch * 8 + jl;
    int c = cf * 16 + (lane & 15);        // permuted output col, 0..511
    int k0 = kb * 32 + ((lane >> 4) << 3);
    const float* wp; int cm;
    if (c < 128)      { wp = A.Wq; cm = c; }
    else if (c < 384) { int u = c - 128, t = u & 7;
                        wp = (t < 4) ? A.Wk : A.Wv; cm = (u >> 3) * 4 + (t & 3); }
    else              { wp = A.Ws; cm = c - 384; }
    short8 h;
    #pragma unroll
    for (int j = 0; j < 8; ++j)
      h[j] = (short)bf16_rne(wp[(size_t)(k0 + j) * 128 + cm]);
    A.frag[g] = h;
  } else if (b < 64) {
    // W2/W3 frags
    int g = (b - 32) * 256 + threadIdx.x;  // 0..8191
    const float* wp; int M, dstbase, gg;
    if (g < 4096) { wp = A.W2; M = 256; dstbase = 8192;  gg = g; }
    else          { wp = A.W3; M = 128; dstbase = 12288; gg = g - 4096; }
    int lane = gg & 63, fid = gg >> 6;
    int nt = fid % (M / 16), kb = fid / (M / 16);
    int n = nt * 16 + (lane & 15);
    int k0 = kb * 32 + ((lane >> 4) << 3);
    short8 h;
    #pragma unroll
    for (int j = 0; j < 8; ++j)
      h[j] = (short)bf16_rne(wp[(size_t)(k0 + j) * M + n]);
    A.frag[dstbase + gg] = h;
  } else if (b < 64 + TBLK) {
    int q = (b - 64) * 256 + threadIdx.x;   // quad id
    const int NT = VV * ED / 4;             // 320000 per table
    if (q < NT) {
      float4 v = *(const float4*)(A.t1 + (size_t)q * 4);
      *(ushort4*)(A.o1 + (size_t)q * 4) = f4b(v);
    } else if (q < 2 * NT) {
      int q2 = q - NT;
      float4 v = *(const float4*)(A.t2 + (size_t)q2 * 4);
      *(ushort4*)(A.o2 + (size_t)q2 * 4) = f4b(v);
    }
  } else if (b < 64 + TBLK + ZBLK) {
    int i = (b - 64 - TBLK) * 256 + threadIdx.x;
    if (i < NM + NO) A.hist[i] = 0;
  } else {
    // permuted bias512
    for (int c = threadIdx.x; c < 512; c += 256) {
      float v;
      if (c < 128)      v = A.bq[c];
      else if (c < 384) { int u = c - 128, t = u & 7;
                          v = (t < 4) ? A.bk[(u >> 3) * 4 + t] : A.bv[(u >> 3) * 4 + (t & 3)]; }
      else              v = A.bs[c - 384];
      A.bias512[c] = v;
    }
  }
}

// ---- embed: fp32-table body (desc): 256 thr = 8 rows x 32 float4-lanes ----
template<int L>
static __device__ __forceinline__ void embed_body_f(const int* __restrict__ tokens,
                                                    const float* __restrict__ table,
                                                    float* __restrict__ out, int blk) {
  const int r = threadIdx.x >> 5, lane = threadIdx.x & 31;
  const int n0 = blk * 8;
  __shared__ int toks[8][L];
  for (int i = threadIdx.x; i < 8 * L; i += 256)
    toks[i / L][i % L] = tokens[(size_t)n0 * L + i];
  __syncthreads();
  float4 acc = make_float4(0.f, 0.f, 0.f, 0.f);
  int cnt = 0;
  #pragma unroll
  for (int l = 0; l < L; ++l) {
    int t = toks[r][l];
    float4 v = *(const float4*)(table + (size_t)t * ED + lane * 4);
    float msk = (t != 0) ? 1.f : 0.f;
    cnt += (t != 0);
    acc.x = fmaf(msk, v.x, acc.x); acc.y = fmaf(msk, v.y, acc.y);
    acc.z = fmaf(msk, v.z, acc.z); acc.w = fmaf(msk, v.w, acc.w);
  }
  float inv = 1.f / (float)(cnt > 0 ? cnt : 1);
  acc.x *= inv; acc.y *= inv; acc.z *= inv; acc.w *= inv;
  *(float4*)(out + (size_t)(n0 + r) * ED + lane * 4) = acc;
}

// ---- embed: bf16-table body: 256 thr = 16 rows x 16 lanes, 16B loads/stores ----
template<int L>
static __device__ __forceinline__ void embed_body16(const int* __restrict__ tokens,
                                                    const unsigned short* __restrict__ table,
                                                    unsigned short* __restrict__ out, int blk) {
  const int r = threadIdx.x >> 4, lane = threadIdx.x & 15;
  const int n0 = blk * 16;
  __shared__ int toks[16][L];
  for (int i = threadIdx.x; i < 16 * L; i += 256)
    toks[i / L][i % L] = tokens[(size_t)n0 * L + i];
  __syncthreads();
  float acc[8] = {};
  int cnt = 0;
  #pragma unroll
  for (int l = 0; l < L; ++l) {
    int t = toks[r][l];
    short8 v = *(const short8*)(table + (size_t)t * ED + lane * 8);
    float msk = (t != 0) ? 1.f : 0.f;
    cnt += (t != 0);
    #pragma unroll
    for (int j = 0; j < 8; ++j)
      acc[j] = fmaf(msk, bf16_to_f((unsigned short)v[j]), acc[j]);
  }
  float inv = 1.f / (float)(cnt > 0 ? cnt : 1);
  short8 o;
  #pragma unroll
  for (int j = 0; j < 8; ++j) o[j] = (short)bf16_rne(acc[j] * inv);
  *(short8*)(out + (size_t)(n0 + r) * ED + lane * 8) = o;
}

// embeddings + edge histogram in one launch, heavy blocks first:
// [0, NM/16) mini | [+NO/16) x | [+BB/8) desc | [+HBLK) hist
#define HBLK ((EM + EO) / 256)   // 1600
#define MBLK (NM / 16)           // 5120
#define XBLK (NO / 16)           // 640
__global__ void __launch_bounds__(256)
embed_all_k(const int* __restrict__ desc_tokens, const float* __restrict__ desc_table,
            float* __restrict__ h_n,
            const int* __restrict__ x_tokens, const unsigned short* __restrict__ ctab2,
            unsigned short* __restrict__ stmt,
            const int* __restrict__ mini_tokens, const unsigned short* __restrict__ ctab,
            unsigned short* __restrict__ miniE,
            const int* __restrict__ mini_dst, const int* __restrict__ dst,
            int* __restrict__ histm, int* __restrict__ histo) {
  int b = blockIdx.x;
  if (b < MBLK) embed_body16<LM>(mini_tokens, ctab, miniE, b);
  else if (b < MBLK + XBLK) embed_body16<LO>(x_tokens, ctab2, stmt, b - MBLK);
  else if (b < MBLK + XBLK + BB / 8)
    embed_body_f<LDE>(desc_tokens, desc_table, h_n, b - MBLK - XBLK);
  else {
    int e = (b - MBLK - XBLK - BB / 8) * 256 + threadIdx.x;   // [0, EM+EO)
    if (e < EM) atomicAdd(&histm[mini_dst[e]], 1);
    else        atomicAdd(&histo[dst[e - EM]], 1);
  }
}

// ================= CSR build: scan_final (self-prefix over raw part) + scatter ========
__global__ void __launch_bounds__(256)
scan_final2_k(const int* __restrict__ hist, const int* __restrict__ part,
              int* __restrict__ offsm, int* __restrict__ curm,
              int* __restrict__ offso, int* __restrict__ curo,
              float* __restrict__ dinv) {
  __shared__ int sd[256], red[256];
  const int b = blockIdx.x, t = threadIdx.x;
  const int i = b * 256 + t;
  const int v = hist[i];
  sd[t] = v; __syncthreads();
  for (int off = 1; off < 256; off <<= 1) {
    int a = (t >= off) ? sd[t - off] : 0;
    __syncthreads(); sd[t] += a; __syncthreads();
  }
  const int excl = sd[t] - v;
  // prefix over raw chunk sums within this segment (NM chunks | NO chunks)
  const int segBase = (b < NM / 256) ? 0 : NM / 256;
  const int myIdx = b - segBase;
  int s = 0;
  for (int k = t; k < myIdx; k += 256) s += part[segBase + k];
  red[t] = s; __syncthreads();
  for (int o = 128; o > 0; o >>= 1) { if (t < o) red[t] += red[t + o]; __syncthreads(); }
  const int off = red[0] + excl;
  if (i < NM) {
    offsm[i] = off; curm[i] = off;
    if (i == NM - 1) offsm[NM] = off + v;
  } else {
    int i2 = i - NM;
    offso[i2] = off; curo[i2] = off;
    if (i2 == NO - 1) offso[NO] = off + v;
    dinv[i2] = 1.f / sqrtf(1.f + (float)v);
  }
}
__global__ void scatter2_k(const int* __restrict__ sm, const int* __restrict__ dm,
                           int* __restrict__ cm, int* __restrict__ km,
                           const int* __restrict__ so, const int* __restrict__ dd,
                           int* __restrict__ co, int* __restrict__ ko) {
  int e = blockIdx.x * 256 + threadIdx.x;
  if (e < EM) {
    int pos = atomicAdd(&cm[dm[e]], 1);
    km[pos] = sm[e];
  } else {
    int e2 = e - EM;
    if (e2 < EO) {
      int pos = atomicAdd(&co[dd[e2]], 1);
      ko[pos] = so[e2];
    }
  }
}

// ======================================================================
// Merged QKVS GEMM v4 + fused chunk_sum (R7-proven):
//   blocks [0,640):      GEMM (XCD-swizzled)
//   blocks [640,1000):   chunk_sum over hist[NM+NO] -> part (raw sums)
// ======================================================================
#define QKVSB (NM / 128)            // 640
#define CSUMB ((NM + NO) / 256)     // 360
__global__ void __launch_bounds__(512)
qkvs_merged_k(const unsigned short* __restrict__ Ab, const short8* __restrict__ Wf,
              const float* __restrict__ bias512, unsigned short* __restrict__ out,
              const int* __restrict__ hist, int* __restrict__ part) {
  __shared__ short8 wlds[2048];          // 32 KB; doubles as per-wave 4KB epilogue / sd
  const int tid = threadIdx.x;
  if (blockIdx.x >= QKVSB) {
    // ---- chunk_sum branch ----
    int* sd = (int*)wlds;
    const int cb = blockIdx.x - QKVSB;
    const int i = cb * 256 + (tid & 255);
    if (tid < 256) sd[tid] = (i < NM + NO) ? hist[i] : 0;
    __syncthreads();
    for (int s = 128; s > 0; s >>= 1) {
      if (tid < s) sd[tid] += sd[tid + s];
      __syncthreads();
    }
    if (tid == 0) part[cb] = sd[0];
    return;
  }
  const int id = blockIdx.x;
  const int blk = (id & 7) * 80 + (id >> 3);   // XCD-bijective swizzle (640 = 8*80)
  const int n0 = blk * 128;
  const int w = tid >> 6, lane = tid & 63;
  const int r = lane & 15, qd = lane >> 4;
  const int node = n0 + w * 16 + r;
  char* myl = (char*)wlds + w * 4096;

  // A fragments for this wave's 16 nodes, full K=128
  short8 a[4];
  #pragma unroll
  for (int kb = 0; kb < 4; ++kb)
    a[kb] = *(const short8*)(Ab + (size_t)node * ED + kb * 32 + qd * 8);

  for (int ch = 0; ch < 4; ++ch) {
    // ---- stage chunk weights into own 4KB region: 4 x (64 lanes x 16B) ----
    {
      const char* gs = (const char*)Wf + (size_t)ch * 32768
                     + (size_t)(w * 4) * 1024 + (size_t)lane * 16;
      char* ls = (char*)wlds + (w * 4) * 1024;   // wave-uniform == own region
      #pragma unroll
      for (int t = 0; t < 4; ++t)
        gl_lds16(gs + t * 1024, ls + t * 1024);
    }
    __syncthreads();   // chunk resident

    f32x4 acc[8];
    #pragma unroll
    for (int jl = 0; jl < 8; ++jl) acc[jl] = (f32x4){0.f, 0.f, 0.f, 0.f};
    #pragma unroll
    for (int kb = 0; kb < 4; ++kb)
      #pragma unroll
      for (int jl = 0; jl < 8; ++jl) {
        short8 wf = *(const short8*)((const char*)wlds
                      + ((size_t)((kb << 3) | jl) * 64 + lane) * 16);
        acc[jl] = __builtin_amdgcn_mfma_f32_16x16x32_bf16(wf, a[kb], acc[jl], 0, 0, 0);
      }
    __syncthreads();   // all waves done reading weights -> LDS reusable

    // epilogue into own 4KB (16 rows x 256B, XOR-swizzled bits 5..7)
    #pragma unroll
    for (int jl = 0; jl < 8; ++jl) {
      const int cf = ch * 8 + jl;
      const float4 bv = *(const float4*)(bias512 + cf * 16 + qd * 4);
      ushort4 o;
      o.x = bf16_rne(acc[jl][0] + bv.x);
      o.y = bf16_rne(acc[jl][1] + bv.y);
      o.z = bf16_rne(acc[jl][2] + bv.z);
      o.w = bf16_rne(acc[jl][3] + bv.w);
      *(ushort4*)(myl + r * 256 + ((jl * 32) ^ ((r & 7) << 5)) + qd * 8) = o;
    }
    // drain: 16 rows x 256B -> global, 16B/lane, 4 rounds of 4 rows
    #pragma unroll
    for (int t = 0; t < 4; ++t) {
      const int rr = t * 4 + qd;
      short8 v = *(const short8*)(myl + rr * 256 + (((lane & 15) * 16) ^ ((rr & 7) << 5)));
      *(short8*)(out + (size_t)(n0 + w * 16 + rr) * 512 + ch * 128 + (lane & 15) * 8) = v;
    }
    __syncthreads();   // drains done before next stage overwrites
  }
}

// ======================================================================
// FUSED TransformerConv + global-attention-combine (R9-proven).
// ======================================================================
__global__ void __launch_bounds__(256)
attn_comb_k(const unsigned short* __restrict__ buf,
            const int* __restrict__ offs, const int* __restrict__ csr,
            const float* __restrict__ Wg, const float* __restrict__ bg,
            const unsigned short* __restrict__ stmt, unsigned short* __restrict__ out) {
  const int g = threadIdx.x >> 5, lane = threadIdx.x & 31;
  const int n = blockIdx.x * 8 + g;          // mini node
  float4 q = b4f(*(const ushort4*)(buf + (size_t)n * 512 + lane * 4));
  float4 sk = b4f(*(const ushort4*)(buf + (size_t)n * 512 + 384 + lane * 4));
  float4 wg = *(const float4*)(Wg + lane * 4);
  int lo = offs[n], hi = offs[n + 1];
  float4 O = make_float4(0.f, 0.f, 0.f, 0.f);
  float m = -INFINITY, l = 0.f;
  for (int base = lo; base < hi; base += 4) {
    int rem = hi - base;                      // >= 1
    int sidx[4];
    #pragma unroll
    for (int i = 0; i < 4; ++i) sidx[i] = (i < rem) ? csr[base + i] : 0;
    short8 kvr[4];
    #pragma unroll
    for (int i = 0; i < 4; ++i)
      kvr[i] = *(const short8*)(buf + (size_t)sidx[i] * 512 + 128 + lane * 8);
    float sc[4]; float4 vt[4];
    #pragma unroll
    for (int i = 0; i < 4; ++i) {
      float4 kt = make_float4(bf16_to_f((unsigned short)kvr[i][0]),
                              bf16_to_f((unsigned short)kvr[i][1]),
                              bf16_to_f((unsigned short)kvr[i][2]),
                              bf16_to_f((unsigned short)kvr[i][3]));
      vt[i] = make_float4(bf16_to_f((unsigned short)kvr[i][4]),
                          bf16_to_f((unsigned short)kvr[i][5]),
                          bf16_to_f((unsigned short)kvr[i][6]),
                          bf16_to_f((unsigned short)kvr[i][7]));
      float p = q.x * kt.x + q.y * kt.y + q.z * kt.z + q.w * kt.w;
      p += __shfl_xor(p, 1, 64);
      p += __shfl_xor(p, 2, 64);
      sc[i] = (i < rem) ? p * 0.25f : -INFINITY;   // 1/sqrt(Dh); pad = no-op
    }
    float mt = fmaxf(fmaxf(sc[0], sc[1]), fmaxf(sc[2], sc[3]));
    float mn = fmaxf(m, mt);                        // finite (rem>=1)
    float scale = __expf(m - mn);                   // first chunk: exp(-inf)=0
    float pe[4];
    #pragma unroll
    for (int i = 0; i < 4; ++i) pe[i] = __expf(sc[i] - mn);   // pads -> 0
    l = l * scale + ((pe[0] + pe[1]) + (pe[2] + pe[3]));
    O.x = fmaf(pe[3], vt[3].x, fmaf(pe[2], vt[2].x, fmaf(pe[1], vt[1].x, fmaf(pe[0], vt[0].x, O.x * scale))));
    O.y = fmaf(pe[3], vt[3].y, fmaf(pe[2], vt[2].y, fmaf(pe[1], vt[1].y, fmaf(pe[0], vt[0].y, O.y * scale))));
    O.z = fmaf(pe[3], vt[3].z, fmaf(pe[2], vt[2].z, fmaf(pe[1], vt[1].z, fmaf(pe[0], vt[0].z, O.z * scale))));
    O.w = fmaf(pe[3], vt[3].w, fmaf(pe[2], vt[2].w, fmaf(pe[1], vt[1].w, fmaf(pe[0], vt[0].w, O.w * scale))));
    m = mn;
  }
  float inv = 1.f / (l + 1e-16f);
  float4 ov = make_float4(O.x * inv + sk.x, O.y * inv + sk.y,
                          O.z * inv + sk.z, O.w * inv + sk.w);
  // gate for this mini
  float ps = ov.x * wg.x + ov.y * wg.y + ov.z * wg.z + ov.w * wg.w;
  #pragma unroll
  for (int o = 1; o <= 16; o <<= 1) ps += __shfl_xor(ps, o, 64);
  __shared__ float outs[8][32][4];   // 4 KB
  __shared__ float gates[8];
  *(float4*)&outs[g][lane][0] = ov;
  if (lane == 0) gates[g] = ps + bg[0];
  __syncthreads();
  if (threadIdx.x < 32) {
    float gm = -INFINITY;
    #pragma unroll
    for (int j = 0; j < 8; ++j) gm = fmaxf(gm, gates[j]);
    float e[8], s = 0.f;
    #pragma unroll
    for (int j = 0; j < 8; ++j) { e[j] = __expf(gates[j] - gm); s += e[j]; }
    float ia = 1.f / (s + 1e-16f);
    float4 acc = make_float4(0.f, 0.f, 0.f, 0.f);
    #pragma unroll
    for (int j = 0; j < 8; ++j) {
      float a = e[j] * ia;
      float4 v = *(const float4*)&outs[j][threadIdx.x][0];
      acc.x = fmaf(a, v.x, acc.x); acc.y = fmaf(a, v.y, acc.y);
      acc.z = fmaf(a, v.z, acc.z); acc.w = fmaf(a, v.w, acc.w);
    }
    float4 o4 = b4f(*(const ushort4*)(stmt + (size_t)blockIdx.x * ED + threadIdx.x * 4));
    acc.x = (acc.x + o4.x) * 0.5f; acc.y = (acc.y + o4.y) * 0.5f;
    acc.z = (acc.z + o4.z) * 0.5f; acc.w = (acc.w + o4.w) * 0.5f;
    *(ushort4*)(out + (size_t)blockIdx.x * ED + threadIdx.x * 4) = f4b(acc);
  }
}

// ======================================================================
// FUSED GCN MLP: gather1 + gemm1(relu,@W2,b2) + gemm2(@W3) in one kernel.
// Per 128-node block (grid = NO/128 = 80):
//  phase A: agg = A_hat * mini_fn for the block's 128 rows -> LDS (swizzled)
//  phase B: h = relu(agg @ W2 + b2) -> same LDS buffer (64KB, swizzled)
//  phase C: t = h @ W3 -> global (consumed by gather2 across blocks)
// A_hat commutes with the right-multiplications, so this equals
// gcn_conv ordering in the reference. LDS 64KB -> 2 blocks/CU.
// ======================================================================
__global__ void __launch_bounds__(512)
mlp_fused_k(const unsigned short* __restrict__ x,   // mini_fn [NO][128]
            const float* __restrict__ dinv,
            const int* __restrict__ offs, const int* __restrict__ csr,
            const short8* __restrict__ W2f, const float* __restrict__ b2,
            const short8* __restrict__ W3f,
            unsigned short* __restrict__ tout) {    // [NO][128]
  __shared__ char buf[128 * 512];   // 64KB: A-tile in [0,32KB), then h-tile full
  const int tid = threadIdx.x;
  const int w = tid >> 6, lane = tid & 63;
  const int half = lane >> 5, cl = lane & 31;
  const int n0 = blockIdx.x * 128;

  // ---- phase A: gather agg rows (full wave per node, dual-half chunk-8) ----
  for (int i = 0; i < 16; ++i) {
    const int rl = w * 16 + i;
    const int n = n0 + rl;
    float di = dinv[n];
    float4 acc = make_float4(0.f, 0.f, 0.f, 0.f);
    if (half == 0) {   // self term once
      float4 xs = b4f(*(const ushort4*)(x + (size_t)n * ED + cl * 4));
      float w0 = di * di;
      acc = make_float4(w0 * xs.x, w0 * xs.y, w0 * xs.z, w0 * xs.w);
    }
    int lo = offs[n], hi = offs[n + 1];
    for (int base = lo; base < hi; base += 8) {
      int sidx[4]; bool ok[4];
      #pragma unroll
      for (int t = 0; t < 4; ++t) {
        int e = base + 2 * t + half;
        ok[t] = e < hi;
        sidx[t] = ok[t] ? csr[e] : 0;
      }
      float dw[4];
      #pragma unroll
      for (int t = 0; t < 4; ++t) dw[t] = ok[t] ? di * dinv[sidx[t]] : 0.f;
      ushort4 vr[4];
      #pragma unroll
      for (int t = 0; t < 4; ++t)
        vr[t] = *(const ushort4*)(x + (size_t)sidx[t] * ED + cl * 4);
      #pragma unroll
      for (int t = 0; t < 4; ++t) {
        float4 v = b4f(vr[t]);
        acc.x = fmaf(dw[t], v.x, acc.x); acc.y = fmaf(dw[t], v.y, acc.y);
        acc.z = fmaf(dw[t], v.z, acc.z); acc.w = fmaf(dw[t], v.w, acc.w);
      }
    }
    acc.x += __shfl_xor(acc.x, 32, 64); acc.y += __shfl_xor(acc.y, 32, 64);
    acc.z += __shfl_xor(acc.z, 32, 64); acc.w += __shfl_xor(acc.w, 32, 64);
    if (half == 0)
      *(ushort4*)(buf + rl * 256 + ((cl * 8) ^ ((rl & 7) << 4))) = f4b(acc);
  }
  __syncthreads();

  // ---- A-frags to regs (swizzled 16B reads, 2-way = free) ----
  const int r = lane & 15, qd = lane >> 4;
  const int row = w * 16 + r;
  short8 a1[4];
  #pragma unroll
  for (int kb = 0; kb < 4; ++kb)
    a1[kb] = *(const short8*)(buf + row * 256 + ((kb * 64 + qd * 16) ^ ((row & 7) << 4)));
  __syncthreads();   // A dead -> buf reusable as h-tile

  // ---- phase B: h = relu(A@W2 + b2) -> LDS [128][512B] ----
  #pragma unroll 4
  for (int cf = 0; cf < 16; ++cf) {
    f32x4 acc = (f32x4){0.f, 0.f, 0.f, 0.f};
    #pragma unroll
    for (int kb = 0; kb < 4; ++kb)
      acc = __builtin_amdgcn_mfma_f32_16x16x32_bf16(
          W2f[((size_t)(kb * 16 + cf)) * 64 + lane], a1[kb], acc, 0, 0, 0);
    const float4 bv = *(const float4*)(b2 + cf * 16 + qd * 4);
    ushort4 o;
    o.x = bf16_rne(fmaxf(acc[0] + bv.x, 0.f));
    o.y = bf16_rne(fmaxf(acc[1] + bv.y, 0.f));
    o.z = bf16_rne(fmaxf(acc[2] + bv.z, 0.f));
    o.w = bf16_rne(fmaxf(acc[3] + bv.w, 0.f));
    *(ushort4*)(buf + row * 512 + ((cf * 32 + qd * 8) ^ ((row & 7) << 4))) = o;
  }
  __syncthreads();

  // ---- phase C: t = h @ W3 -> global ----
  short8 a2[8];
  #pragma unroll
  for (int kb = 0; kb < 8; ++kb)
    a2[kb] = *(const short8*)(buf + row * 512 + ((kb * 64 + qd * 16) ^ ((row & 7) << 4)));
  #pragma unroll
  for (int cf = 0; cf < 8; ++cf) {
    f32x4 acc = (f32x4){0.f, 0.f, 0.f, 0.f};
    #pragma unroll
    for (int kb = 0; kb < 8; ++kb)
      acc = __builtin_amdgcn_mfma_f32_16x16x32_bf16(
          W3f[((size_t)(kb * 8 + cf)) * 64 + lane], a2[kb], acc, 0, 0, 0);
    ushort4 o = make_ushort4(bf16_rne(acc[0]), bf16_rne(acc[1]),
                             bf16_rne(acc[2]), bf16_rne(acc[3]));
    *(ushort4*)(tout + (size_t)(n0 + row) * ED + cf * 16 + qd * 4) = o;
  }
}

// ============ GCN gather (bf16): FULL WAVE per node, dual-half chunk-8 ========
__global__ void __launch_bounds__(256)
gcn_gather_b_k(const unsigned short* __restrict__ x, const float* __restrict__ dinv,
               const int* __restrict__ offs, const int* __restrict__ csr,
               const float* __restrict__ bias, unsigned short* __restrict__ out,
               const float* __restrict__ Wg, const float* __restrict__ bg,
               float* __restrict__ gateOut) {
  const int wv = threadIdx.x >> 6, lane = threadIdx.x & 63;
  const int half = lane >> 5, cl = lane & 31;
  const int n = blockIdx.x * 4 + wv;
  float di = dinv[n];
  float4 acc = make_float4(0.f, 0.f, 0.f, 0.f);
  if (half == 0) {   // self term once
    float4 xs = b4f(*(const ushort4*)(x + (size_t)n * ED + cl * 4));
    float w0 = di * di;
    acc = make_float4(w0 * xs.x, w0 * xs.y, w0 * xs.z, w0 * xs.w);
  }
  int lo = offs[n], hi = offs[n + 1];
  for (int base = lo; base < hi; base += 8) {
    int sidx[4]; bool ok[4];
    #pragma unroll
    for (int i = 0; i < 4; ++i) {
      int e = base + 2 * i + half;
      ok[i] = e < hi;
      sidx[i] = ok[i] ? csr[e] : 0;
    }
    float dw[4];
    #pragma unroll
    for (int i = 0; i < 4; ++i) dw[i] = ok[i] ? di * dinv[sidx[i]] : 0.f;
    ushort4 vr[4];
    #pragma unroll
    for (int i = 0; i < 4; ++i)
      vr[i] = *(const ushort4*)(x + (size_t)sidx[i] * ED + cl * 4);
    #pragma unroll
    for (int i = 0; i < 4; ++i) {
      float4 v = b4f(vr[i]);
      acc.x = fmaf(dw[i], v.x, acc.x); acc.y = fmaf(dw[i], v.y, acc.y);
      acc.z = fmaf(dw[i], v.z, acc.z); acc.w = fmaf(dw[i], v.w, acc.w);
    }
  }
  // merge halves
  acc.x += __shfl_xor(acc.x, 32, 64); acc.y += __shfl_xor(acc.y, 32, 64);
  acc.z += __shfl_xor(acc.z, 32, 64); acc.w += __shfl_xor(acc.w, 32, 64);
  if (bias) {
    float4 b4 = *(const float4*)(bias + cl * 4);
    acc.x += b4.x; acc.y += b4.y; acc.z += b4.z; acc.w += b4.w;
  }
  if (half == 0)
    *(ushort4*)(out + (size_t)n * ED + cl * 4) = f4b(acc);
  if (gateOut) {
    float4 wg = *(const float4*)(Wg + cl * 4);
    float ps = acc.x * wg.x + acc.y * wg.y + acc.z * wg.z + acc.w * wg.w;
    #pragma unroll
    for (int o = 1; o <= 16; o <<= 1) ps += __shfl_xor(ps, o, 64);
    if (lane == 0) gateOut[n] = ps + bg[0];
  }
}

// ============ final global attention NO->BB (bf16 x) with cosine fused ====
static __device__ __forceinline__ int lower_bound_d(const int* a, int n, int key) {
  int lo = 0, hi = n;
  while (lo < hi) { int mid = (lo + hi) >> 1; if (a[mid] < key) lo = mid + 1; else hi = mid; }
  return lo;
}
__global__ void __launch_bounds__(128)
gattn_cos_k(const unsigned short* __restrict__ x, const float* __restrict__ gate,
            const int* __restrict__ seg, int Ntot,
            const float* __restrict__ hn, float* __restrict__ outp) {
  const int g = threadIdx.x >> 5, lane = threadIdx.x & 31;
  const int n = blockIdx.x * 4 + g;
  __shared__ int sh[4][2];
  if (lane == 0) {
    sh[g][0] = lower_bound_d(seg, Ntot, n);
    sh[g][1] = lower_bound_d(seg, Ntot, n + 1);
  }
  __syncthreads();
  int lo = sh[g][0], hi = sh[g][1];
  float m = -INFINITY;
  for (int j = lo; j < hi; ++j) m = fmaxf(m, gate[j]);
  float ssum = 0.f;
  for (int j = lo; j < hi; ++j) ssum += __expf(gate[j] - m);
  float inv = 1.f / (ssum + 1e-16f);
  float4 acc = make_float4(0.f, 0.f, 0.f, 0.f);
  for (int j = lo; j < hi; ++j) {
    float a = __expf(gate[j] - m) * inv;
    float4 v = b4f(*(const ushort4*)(x + (size_t)j * ED + lane * 4));
    acc.x = fmaf(a, v.x, acc.x); acc.y = fmaf(a, v.y, acc.y);
    acc.z = fmaf(a, v.z, acc.z); acc.w = fmaf(a, v.w, acc.w);
  }
  float4 hv = *(const float4*)(hn + (size_t)n * ED + lane * 4);
  float dot = acc.x * hv.x + acc.y * hv.y + acc.z * hv.z + acc.w * hv.w;
  float na  = acc.x * acc.x + acc.y * acc.y + acc.z * acc.z + acc.w * acc.w;
  float nb  = hv.x * hv.x + hv.y * hv.y + hv.z * hv.z + hv.w * hv.w;
  #pragma unroll
  for (int o = 1; o <= 16; o <<= 1) {
    dot += __shfl_xor(dot, o, 64);
    na  += __shfl_xor(na,  o, 64);
    nb  += __shfl_xor(nb,  o, 64);
  }
  if (lane == 0)
    outp[n] = dot / (fmaxf(sqrtf(na), 1e-8f) * fmaxf(sqrtf(nb), 1e-8f));
}

// ---- workspace layout (4-byte element offsets) ----
constexpr size_t OFF_HN    = 0;                                  // BB*ED
constexpr size_t OFF_STMT  = OFF_HN    + (size_t)BB * ED;        // NO*ED (bf16 in half)
constexpr size_t OFF_A     = OFF_STMT  + (size_t)NO * ED;        // NM*ED (miniE bf16 -> recycled)
constexpr size_t OFF_CT    = OFF_A     + (size_t)NM * ED;        // VV*ED floats: 2 bf16 tables
constexpr size_t OFF_QKVS  = OFF_CT    + (size_t)VV * ED;        // NM*256 floats = bf16 [NM][512]
constexpr size_t T0        = OFF_QKVS  + (size_t)NM * 256;
constexpr size_t OFF_GATE  = T0;                                 // NM (unused now)
constexpr size_t OFF_GATE2 = OFF_GATE  + (size_t)NM;             // NO
constexpr size_t OFF_DINV  = OFF_GATE2 + (size_t)NO;             // NO
constexpr size_t OFF_HISTM = OFF_DINV  + (size_t)NO;             // NM (int)
constexpr size_t OFF_HISTO = OFF_HISTM + (size_t)NM;             // NO (adjacent -> concat scan)
constexpr size_t OFF_OFFSM = OFF_HISTO + (size_t)NO;             // NM+1
constexpr size_t OFF_CURM  = OFF_OFFSM + (size_t)NM + 1;         // NM
constexpr size_t OFF_CSRM  = OFF_CURM  + (size_t)NM;             // EM
constexpr size_t OFF_OFFSO = OFF_CSRM  + (size_t)EM;             // NO+1
constexpr size_t OFF_CURO  = OFF_OFFSO + (size_t)NO + 1;         // NO
constexpr size_t OFF_CSRO  = OFF_CURO  + (size_t)NO;             // EO
constexpr size_t OFF_PART  = OFF_CSRO  + (size_t)EO;             // 512 (int)
constexpr size_t OFF_B512  = OFF_PART  + 512;                    // 512 floats (permuted bias)
constexpr size_t OFF_WFHI  = OFF_B512  + 512;                    // 65536 floats (16384 short8)
// region-A recycling after qkvs (miniE dead): all bf16
constexpr size_t OFF_MFN   = OFF_A;                              // NO*ED (bf16)
constexpr size_t OFF_T     = OFF_MFN   + (size_t)NO * ED;        // NO*ED (bf16)
constexpr size_t OFF_FIN   = OFF_T     + (size_t)NO * ED;        // NO*ED (bf16)

extern "C" void kernel_launch(void* const* d_in, const int* in_sizes, int n_in,
                              void* d_out, int out_size, void* d_ws, size_t ws_size,
                              hipStream_t stream) {
  const int* desc_tokens = (const int*)d_in[0];
  const int* x_tokens    = (const int*)d_in[1];
  const int* mini_tokens = (const int*)d_in[2];
  const int* src         = (const int*)d_in[3];
  const int* dst         = (const int*)d_in[4];
  const int* mini_src    = (const int*)d_in[5];
  const int* mini_dst    = (const int*)d_in[6];
  const int* mini_batch  = (const int*)d_in[7];
  const int* node_batch  = (const int*)d_in[8];
  const float* desc_table  = (const float*)d_in[9];
  const float* code_table  = (const float*)d_in[10];
  const float* code_table2 = (const float*)d_in[11];
  const float* Wq = (const float*)d_in[12]; const float* bq = (const float*)d_in[13];
  const float* Wk = (const float*)d_in[14]; const float* bk = (const float*)d_in[15];
  const float* Wv = (const float*)d_in[16]; const float* bv = (const float*)d_in[17];
  const float* Wskip = (const float*)d_in[18]; const float* bskip = (const float*)d_in[19];
  const float* W2 = (const float*)d_in[20]; const float* b2 = (const float*)d_in[21];
  const float* W3 = (const float*)d_in[22]; const float* b3 = (const float*)d_in[23];
  const float* Wg = (const float*)d_in[24]; const float* bg = (const float*)d_in[25];
  (void)mini_batch;

  float* ws = (float*)d_ws;
  float* h_n   = ws + OFF_HN;
  unsigned short* stmt_b  = (unsigned short*)(ws + OFF_STMT);
  unsigned short* miniE_b = (unsigned short*)(ws + OFF_A);     // bf16 [NM][128]
  unsigned short* ctab_b  = (unsigned short*)(ws + OFF_CT);
  unsigned short* ctab2_b = ctab_b + (size_t)VV * ED;
  unsigned short* qkvs_b  = (unsigned short*)(ws + OFF_QKVS);  // bf16 [NM][512]
  float* gate2 = ws + OFF_GATE2;
  float* dinv  = ws + OFF_DINV;
  int* histm = (int*)(ws + OFF_HISTM);
  int* histo = (int*)(ws + OFF_HISTO);
  int* offsm = (int*)(ws + OFF_OFFSM);
  int* curm  = (int*)(ws + OFF_CURM);
  int* csrm  = (int*)(ws + OFF_CSRM);
  int* offso = (int*)(ws + OFF_OFFSO);
  int* curo  = (int*)(ws + OFF_CURO);
  int* csro  = (int*)(ws + OFF_CSRO);
  int* part  = (int*)(ws + OFF_PART);
  float* bias512 = ws + OFF_B512;
  short8* wfrag = (short8*)(ws + OFF_WFHI);
  unsigned short* mini_fn_b = (unsigned short*)(ws + OFF_MFN);
  unsigned short* tbuf_b    = (unsigned short*)(ws + OFF_T);
  unsigned short* finalS_b  = (unsigned short*)(ws + OFF_FIN);
  float* outp    = (float*)d_out;

  // ---- conversions + hist zeroing in ONE launch ----
  ConvArgs ca;
  ca.Wq = Wq; ca.Wk = Wk; ca.Wv = Wv; ca.Ws = Wskip; ca.W2 = W2; ca.W3 = W3;
  ca.bq = bq; ca.bk = bk; ca.bv = bv; ca.bs = bskip;
  ca.frag = wfrag; ca.bias512 = bias512;
  ca.t1 = code_table;  ca.o1 = ctab_b;
  ca.t2 = code_table2; ca.o2 = ctab2_b;
  ca.hist = histm;
  conv_all_k<<<64 + TBLK + ZBLK + 1, 256, 0, stream>>>(ca);

  // ---- embeddings + edge histogram in one launch ----
  embed_all_k<<<MBLK + XBLK + BB / 8 + HBLK, 256, 0, stream>>>(
      desc_tokens, desc_table, h_n, x_tokens, ctab2_b, stmt_b,
      mini_tokens, ctab_b, miniE_b, mini_dst, dst, histm, histo);

  // ---- merged Q|KV|Skip projection + fused chunk_sum ----
  qkvs_merged_k<<<QKVSB + CSUMB, 512, 0, stream>>>(miniE_b, wfrag, bias512, qkvs_b,
                                                   histm, part);

  // ---- CSR build: scan_final (self-prefix) + scatter ----
  scan_final2_k<<<(NM + NO) / 256, 256, 0, stream>>>(histm, part, offsm, curm,
                                                     offso, curo, dinv);
  scatter2_k<<<nblk(EM + EO, 256), 256, 0, stream>>>(mini_src, mini_dst, curm, csrm,
                                                     src, dst, curo, csro);

  // ---- FUSED transformer conv + global attention mini->NO + combine ----
  attn_comb_k<<<NO, 256, 0, stream>>>(qkvs_b, offsm, csrm, Wg, bg, stmt_b, mini_fn_b);

  // ---- FUSED GCN MLP: gather1 + relu(·@W2+b2) + ·@W3 -> t ----
  mlp_fused_k<<<NO / 128, 512, 0, stream>>>(mini_fn_b, dinv, offso, csro,
                                            wfrag + 8192, b2, wfrag + 12288, tbuf_b);

  // ---- GCN conv 2 aggregation: final = A_hat * t + b3 (+ gate2) ----
  gcn_gather_b_k<<<NO / 4, 256, 0, stream>>>(tbuf_b, dinv, offso, csro, b3, finalS_b,
                                             Wg, bg, gate2);

  // ---- global attention NO -> BB with fused cosine -> d_out [BB] ----
  gattn_cos_k<<<BB / 4, 128, 0, stream>>>(finalS_b, gate2, node_batch, NO, h_n, outp);
}

// Round 11
// 318.482 us; speedup vs baseline: 1.1051x; 1.1051x over previous
//
#include <hip/hip_runtime.h>
#include <hip/hip_bf16.h>
#include <math.h>

// Problem dims (fixed by reference)
#define BB   256      // batch
#define LDE  64       // desc tokens len
#define NO   10240    // outer nodes
#define LO   32       // x tokens len
#define NM   81920    // mini nodes
#define LM   16       // mini tokens len
#define EO   81920    // outer edges
#define EM   327680   // mini edges
#define ED   128      // embed dim E
#define HIDD 256      // hidden
#define NH   8        // heads
#define DH   16       // head dim
#define VV   10000    // vocab

static inline int nblk(long long n, int b) { return (int)((n + b - 1) / b); }

typedef __attribute__((ext_vector_type(8))) short short8;
typedef __attribute__((ext_vector_type(4))) float f32x4;

// ---- fp32 <-> bf16 (RNE) helpers ----
static __device__ __forceinline__ unsigned short bf16_rne(float f) {
  unsigned u = __float_as_uint(f);
  return (unsigned short)((u + 0x7fffu + ((u >> 16) & 1u)) >> 16);
}
static __device__ __forceinline__ float bf16_to_f(unsigned short h) {
  return __uint_as_float(((unsigned)h) << 16);
}
static __device__ __forceinline__ float4 b4f(ushort4 h) {
  return make_float4(bf16_to_f(h.x), bf16_to_f(h.y), bf16_to_f(h.z), bf16_to_f(h.w));
}
static __device__ __forceinline__ ushort4 f4b(float4 v) {
  return make_ushort4(bf16_rne(v.x), bf16_rne(v.y), bf16_rne(v.z), bf16_rne(v.w));
}

// async global->LDS, 16B/lane. LDS dest must be wave-uniform base; global src per-lane.
static __device__ __forceinline__ void gl_lds16(const void* g, void* l) {
  __builtin_amdgcn_global_load_lds(
      (const __attribute__((address_space(1))) unsigned int*)g,
      (__attribute__((address_space(3))) unsigned int*)l, 16, 0, 0);
}

// ======================================================================
// Conversion kernel
// ======================================================================
struct ConvArgs {
  const float *Wq, *Wk, *Wv, *Ws, *W2, *W3;
  const float *bq, *bk, *bv, *bs;
  short8* frag;            // 16384 octets: [0,8192) QKVS, [8192,12288) W2, [12288,16384) W3
  float* bias512;
  const float* t1; unsigned short* o1;
  const float* t2; unsigned short* o2;
  int* hist;
};
#define TBLK (2 * VV * ED / 4 / 256)      // 2500 table blocks
#define ZBLK ((NM + NO) / 256)            // 360 hist-zero blocks
__global__ void __launch_bounds__(256)
conv_all_k(ConvArgs A) {
  int b = blockIdx.x;
  if (b < 32) {
    // merged QKVS frags, chunk-major: octet g in [0,8192)
    int g = b * 256 + threadIdx.x;
    int lane = g & 63, f = g >> 6;        // f = (ch<<5)|(kb<<3)|jl
    int jl = f & 7, kb = (f >> 3) & 3, ch = f >> 5;
    int cf = ch * 8 + jl;
    int c = cf * 16 + (lane & 15);        // permuted output col, 0..511
    int k0 = kb * 32 + ((lane >> 4) << 3);
    const float* wp; int cm;
    if (c < 128)      { wp = A.Wq; cm = c; }
    else if (c < 384) { int u = c - 128, t = u & 7;
                        wp = (t < 4) ? A.Wk : A.Wv; cm = (u >> 3) * 4 + (t & 3); }
    else              { wp = A.Ws; cm = c - 384; }
    short8 h;
    #pragma unroll
    for (int j = 0; j < 8; ++j)
      h[j] = (short)bf16_rne(wp[(size_t)(k0 + j) * 128 + cm]);
    A.frag[g] = h;
  } else if (b < 64) {
    // W2/W3 frags
    int g = (b - 32) * 256 + threadIdx.x;  // 0..8191
    const float* wp; int M, dstbase, gg;
    if (g < 4096) { wp = A.W2; M = 256; dstbase = 8192;  gg = g; }
    else          { wp = A.W3; M = 128; dstbase = 12288; gg = g - 4096; }
    int lane = gg & 63, fid = gg >> 6;
    int nt = fid % (M / 16), kb = fid / (M / 16);
    int n = nt * 16 + (lane & 15);
    int k0 = kb * 32 + ((lane >> 4) << 3);
    short8 h;
    #pragma unroll
    for (int j = 0; j < 8; ++j)
      h[j] = (short)bf16_rne(wp[(size_t)(k0 + j) * M + n]);
    A.frag[dstbase + gg] = h;
  } else if (b < 64 + TBLK) {
    int q = (b - 64) * 256 + threadIdx.x;   // quad id
    const int NT = VV * ED / 4;             // 320000 per table
    if (q < NT) {
      float4 v = *(const float4*)(A.t1 + (size_t)q * 4);
      *(ushort4*)(A.o1 + (size_t)q * 4) = f4b(v);
    } else if (q < 2 * NT) {
      int q2 = q - NT;
      float4 v = *(const float4*)(A.t2 + (size_t)q2 * 4);
      *(ushort4*)(A.o2 + (size_t)q2 * 4) = f4b(v);
    }
  } else if (b < 64 + TBLK + ZBLK) {
    int i = (b - 64 - TBLK) * 256 + threadIdx.x;
    if (i < NM + NO) A.hist[i] = 0;
  } else {
    // permuted bias512
    for (int c = threadIdx.x; c < 512; c += 256) {
      float v;
      if (c < 128)      v = A.bq[c];
      else if (c < 384) { int u = c - 128, t = u & 7;
                          v = (t < 4) ? A.bk[(u >> 3) * 4 + t] : A.bv[(u >> 3) * 4 + (t & 3)]; }
      else              v = A.bs[c - 384];
      A.bias512[c] = v;
    }
  }
}

// ---- embed: fp32-table body (desc): 256 thr = 8 rows x 32 float4-lanes ----
template<int L>
static __device__ __forceinline__ void embed_body_f(const int* __restrict__ tokens,
                                                    const float* __restrict__ table,
                                                    float* __restrict__ out, int blk) {
  const int r = threadIdx.x >> 5, lane = threadIdx.x & 31;
  const int n0 = blk * 8;
  __shared__ int toks[8][L];
  for (int i = threadIdx.x; i < 8 * L; i += 256)
    toks[i / L][i % L] = tokens[(size_t)n0 * L + i];
  __syncthreads();
  float4 acc = make_float4(0.f, 0.f, 0.f, 0.f);
  int cnt = 0;
  #pragma unroll
  for (int l = 0; l < L; ++l) {
    int t = toks[r][l];
    float4 v = *(const float4*)(table + (size_t)t * ED + lane * 4);
    float msk = (t != 0) ? 1.f : 0.f;
    cnt += (t != 0);
    acc.x = fmaf(msk, v.x, acc.x); acc.y = fmaf(msk, v.y, acc.y);
    acc.z = fmaf(msk, v.z, acc.z); acc.w = fmaf(msk, v.w, acc.w);
  }
  float inv = 1.f / (float)(cnt > 0 ? cnt : 1);
  acc.x *= inv; acc.y *= inv; acc.z *= inv; acc.w *= inv;
  *(float4*)(out + (size_t)(n0 + r) * ED + lane * 4) = acc;
}

// ---- embed: bf16-table body: 256 thr = 16 rows x 16 lanes, 16B loads/stores ----
template<int L>
static __device__ __forceinline__ void embed_body16(const int* __restrict__ tokens,
                                                    const unsigned short* __restrict__ table,
                                                    unsigned short* __restrict__ out, int blk) {
  const int r = threadIdx.x >> 4, lane = threadIdx.x & 15;
  const int n0 = blk * 16;
  __shared__ int toks[16][L];
  for (int i = threadIdx.x; i < 16 * L; i += 256)
    toks[i / L][i % L] = tokens[(size_t)n0 * L + i];
  __syncthreads();
  float acc[8] = {};
  int cnt = 0;
  #pragma unroll
  for (int l = 0; l < L; ++l) {
    int t = toks[r][l];
    short8 v = *(const short8*)(table + (size_t)t * ED + lane * 8);
    float msk = (t != 0) ? 1.f : 0.f;
    cnt += (t != 0);
    #pragma unroll
    for (int j = 0; j < 8; ++j)
      acc[j] = fmaf(msk, bf16_to_f((unsigned short)v[j]), acc[j]);
  }
  float inv = 1.f / (float)(cnt > 0 ? cnt : 1);
  short8 o;
  #pragma unroll
  for (int j = 0; j < 8; ++j) o[j] = (short)bf16_rne(acc[j] * inv);
  *(short8*)(out + (size_t)(n0 + r) * ED + lane * 8) = o;
}

// embeddings + edge histogram in one launch, heavy blocks first:
// [0, NM/16) mini | [+NO/16) x | [+BB/8) desc | [+HBLK) hist
#define HBLK ((EM + EO) / 256)   // 1600
#define MBLK (NM / 16)           // 5120
#define XBLK (NO / 16)           // 640
__global__ void __launch_bounds__(256)
embed_all_k(const int* __restrict__ desc_tokens, const float* __restrict__ desc_table,
            float* __restrict__ h_n,
            const int* __restrict__ x_tokens, const unsigned short* __restrict__ ctab2,
            unsigned short* __restrict__ stmt,
            const int* __restrict__ mini_tokens, const unsigned short* __restrict__ ctab,
            unsigned short* __restrict__ miniE,
            const int* __restrict__ mini_dst, const int* __restrict__ dst,
            int* __restrict__ histm, int* __restrict__ histo) {
  int b = blockIdx.x;
  if (b < MBLK) embed_body16<LM>(mini_tokens, ctab, miniE, b);
  else if (b < MBLK + XBLK) embed_body16<LO>(x_tokens, ctab2, stmt, b - MBLK);
  else if (b < MBLK + XBLK + BB / 8)
    embed_body_f<LDE>(desc_tokens, desc_table, h_n, b - MBLK - XBLK);
  else {
    int e = (b - MBLK - XBLK - BB / 8) * 256 + threadIdx.x;   // [0, EM+EO)
    if (e < EM) atomicAdd(&histm[mini_dst[e]], 1);
    else        atomicAdd(&histo[dst[e - EM]], 1);
  }
}

// ================= CSR build: scan_final (self-prefix over raw part) + scatter ========
__global__ void __launch_bounds__(256)
scan_final2_k(const int* __restrict__ hist, const int* __restrict__ part,
              int* __restrict__ offsm, int* __restrict__ curm,
              int* __restrict__ offso, int* __restrict__ curo,
              float* __restrict__ dinv) {
  __shared__ int sd[256], red[256];
  const int b = blockIdx.x, t = threadIdx.x;
  const int i = b * 256 + t;
  const int v = hist[i];
  sd[t] = v; __syncthreads();
  for (int off = 1; off < 256; off <<= 1) {
    int a = (t >= off) ? sd[t - off] : 0;
    __syncthreads(); sd[t] += a; __syncthreads();
  }
  const int excl = sd[t] - v;
  // prefix over raw chunk sums within this segment (NM chunks | NO chunks)
  const int segBase = (b < NM / 256) ? 0 : NM / 256;
  const int myIdx = b - segBase;
  int s = 0;
  for (int k = t; k < myIdx; k += 256) s += part[segBase + k];
  red[t] = s; __syncthreads();
  for (int o = 128; o > 0; o >>= 1) { if (t < o) red[t] += red[t + o]; __syncthreads(); }
  const int off = red[0] + excl;
  if (i < NM) {
    offsm[i] = off; curm[i] = off;
    if (i == NM - 1) offsm[NM] = off + v;
  } else {
    int i2 = i - NM;
    offso[i2] = off; curo[i2] = off;
    if (i2 == NO - 1) offso[NO] = off + v;
    dinv[i2] = 1.f / sqrtf(1.f + (float)v);
  }
}
__global__ void scatter2_k(const int* __restrict__ sm, const int* __restrict__ dm,
                           int* __restrict__ cm, int* __restrict__ km,
                           const int* __restrict__ so, const int* __restrict__ dd,
                           int* __restrict__ co, int* __restrict__ ko) {
  int e = blockIdx.x * 256 + threadIdx.x;
  if (e < EM) {
    int pos = atomicAdd(&cm[dm[e]], 1);
    km[pos] = sm[e];
  } else {
    int e2 = e - EM;
    if (e2 < EO) {
      int pos = atomicAdd(&co[dd[e2]], 1);
      ko[pos] = so[e2];
    }
  }
}

// ======================================================================
// Merged QKVS GEMM v4 + fused chunk_sum (R7-proven):
//   blocks [0,640):      GEMM (XCD-swizzled)
//   blocks [640,1000):   chunk_sum over hist[NM+NO] -> part (raw sums)
// ======================================================================
#define QKVSB (NM / 128)            // 640
#define CSUMB ((NM + NO) / 256)     // 360
__global__ void __launch_bounds__(512)
qkvs_merged_k(const unsigned short* __restrict__ Ab, const short8* __restrict__ Wf,
              const float* __restrict__ bias512, unsigned short* __restrict__ out,
              const int* __restrict__ hist, int* __restrict__ part) {
  __shared__ short8 wlds[2048];          // 32 KB; doubles as per-wave 4KB epilogue / sd
  const int tid = threadIdx.x;
  if (blockIdx.x >= QKVSB) {
    // ---- chunk_sum branch ----
    int* sd = (int*)wlds;
    const int cb = blockIdx.x - QKVSB;
    const int i = cb * 256 + (tid & 255);
    if (tid < 256) sd[tid] = (i < NM + NO) ? hist[i] : 0;
    __syncthreads();
    for (int s = 128; s > 0; s >>= 1) {
      if (tid < s) sd[tid] += sd[tid + s];
      __syncthreads();
    }
    if (tid == 0) part[cb] = sd[0];
    return;
  }
  const int id = blockIdx.x;
  const int blk = (id & 7) * 80 + (id >> 3);   // XCD-bijective swizzle (640 = 8*80)
  const int n0 = blk * 128;
  const int w = tid >> 6, lane = tid & 63;
  const int r = lane & 15, qd = lane >> 4;
  const int node = n0 + w * 16 + r;
  char* myl = (char*)wlds + w * 4096;

  // A fragments for this wave's 16 nodes, full K=128
  short8 a[4];
  #pragma unroll
  for (int kb = 0; kb < 4; ++kb)
    a[kb] = *(const short8*)(Ab + (size_t)node * ED + kb * 32 + qd * 8);

  for (int ch = 0; ch < 4; ++ch) {
    // ---- stage chunk weights into own 4KB region: 4 x (64 lanes x 16B) ----
    {
      const char* gs = (const char*)Wf + (size_t)ch * 32768
                     + (size_t)(w * 4) * 1024 + (size_t)lane * 16;
      char* ls = (char*)wlds + (w * 4) * 1024;   // wave-uniform == own region
      #pragma unroll
      for (int t = 0; t < 4; ++t)
        gl_lds16(gs + t * 1024, ls + t * 1024);
    }
    __syncthreads();   // chunk resident

    f32x4 acc[8];
    #pragma unroll
    for (int jl = 0; jl < 8; ++jl) acc[jl] = (f32x4){0.f, 0.f, 0.f, 0.f};
    #pragma unroll
    for (int kb = 0; kb < 4; ++kb)
      #pragma unroll
      for (int jl = 0; jl < 8; ++jl) {
        short8 wf = *(const short8*)((const char*)wlds
                      + ((size_t)((kb << 3) | jl) * 64 + lane) * 16);
        acc[jl] = __builtin_amdgcn_mfma_f32_16x16x32_bf16(wf, a[kb], acc[jl], 0, 0, 0);
      }
    __syncthreads();   // all waves done reading weights -> LDS reusable

    // epilogue into own 4KB (16 rows x 256B, XOR-swizzled bits 5..7)
    #pragma unroll
    for (int jl = 0; jl < 8; ++jl) {
      const int cf = ch * 8 + jl;
      const float4 bv = *(const float4*)(bias512 + cf * 16 + qd * 4);
      ushort4 o;
      o.x = bf16_rne(acc[jl][0] + bv.x);
      o.y = bf16_rne(acc[jl][1] + bv.y);
      o.z = bf16_rne(acc[jl][2] + bv.z);
      o.w = bf16_rne(acc[jl][3] + bv.w);
      *(ushort4*)(myl + r * 256 + ((jl * 32) ^ ((r & 7) << 5)) + qd * 8) = o;
    }
    // drain: 16 rows x 256B -> global, 16B/lane, 4 rounds of 4 rows
    #pragma unroll
    for (int t = 0; t < 4; ++t) {
      const int rr = t * 4 + qd;
      short8 v = *(const short8*)(myl + rr * 256 + (((lane & 15) * 16) ^ ((rr & 7) << 5)));
      *(short8*)(out + (size_t)(n0 + w * 16 + rr) * 512 + ch * 128 + (lane & 15) * 8) = v;
    }
    __syncthreads();   // drains done before next stage overwrites
  }
}

// ======================================================================
// FUSED TransformerConv + global-attention-combine (R9-proven).
// ======================================================================
__global__ void __launch_bounds__(256)
attn_comb_k(const unsigned short* __restrict__ buf,
            const int* __restrict__ offs, const int* __restrict__ csr,
            const float* __restrict__ Wg, const float* __restrict__ bg,
            const unsigned short* __restrict__ stmt, unsigned short* __restrict__ out) {
  const int g = threadIdx.x >> 5, lane = threadIdx.x & 31;
  const int n = blockIdx.x * 8 + g;          // mini node
  float4 q = b4f(*(const ushort4*)(buf + (size_t)n * 512 + lane * 4));
  float4 sk = b4f(*(const ushort4*)(buf + (size_t)n * 512 + 384 + lane * 4));
  float4 wg = *(const float4*)(Wg + lane * 4);
  int lo = offs[n], hi = offs[n + 1];
  float4 O = make_float4(0.f, 0.f, 0.f, 0.f);
  float m = -INFINITY, l = 0.f;
  for (int base = lo; base < hi; base += 4) {
    int rem = hi - base;                      // >= 1
    int sidx[4];
    #pragma unroll
    for (int i = 0; i < 4; ++i) sidx[i] = (i < rem) ? csr[base + i] : 0;
    short8 kvr[4];
    #pragma unroll
    for (int i = 0; i < 4; ++i)
      kvr[i] = *(const short8*)(buf + (size_t)sidx[i] * 512 + 128 + lane * 8);
    float sc[4]; float4 vt[4];
    #pragma unroll
    for (int i = 0; i < 4; ++i) {
      float4 kt = make_float4(bf16_to_f((unsigned short)kvr[i][0]),
                              bf16_to_f((unsigned short)kvr[i][1]),
                              bf16_to_f((unsigned short)kvr[i][2]),
                              bf16_to_f((unsigned short)kvr[i][3]));
      vt[i] = make_float4(bf16_to_f((unsigned short)kvr[i][4]),
                          bf16_to_f((unsigned short)kvr[i][5]),
                          bf16_to_f((unsigned short)kvr[i][6]),
                          bf16_to_f((unsigned short)kvr[i][7]));
      float p = q.x * kt.x + q.y * kt.y + q.z * kt.z + q.w * kt.w;
      p += __shfl_xor(p, 1, 64);
      p += __shfl_xor(p, 2, 64);
      sc[i] = (i < rem) ? p * 0.25f : -INFINITY;   // 1/sqrt(Dh); pad = no-op
    }
    float mt = fmaxf(fmaxf(sc[0], sc[1]), fmaxf(sc[2], sc[3]));
    float mn = fmaxf(m, mt);                        // finite (rem>=1)
    float scale = __expf(m - mn);                   // first chunk: exp(-inf)=0
    float pe[4];
    #pragma unroll
    for (int i = 0; i < 4; ++i) pe[i] = __expf(sc[i] - mn);   // pads -> 0
    l = l * scale + ((pe[0] + pe[1]) + (pe[2] + pe[3]));
    O.x = fmaf(pe[3], vt[3].x, fmaf(pe[2], vt[2].x, fmaf(pe[1], vt[1].x, fmaf(pe[0], vt[0].x, O.x * scale))));
    O.y = fmaf(pe[3], vt[3].y, fmaf(pe[2], vt[2].y, fmaf(pe[1], vt[1].y, fmaf(pe[0], vt[0].y, O.y * scale))));
    O.z = fmaf(pe[3], vt[3].z, fmaf(pe[2], vt[2].z, fmaf(pe[1], vt[1].z, fmaf(pe[0], vt[0].z, O.z * scale))));
    O.w = fmaf(pe[3], vt[3].w, fmaf(pe[2], vt[2].w, fmaf(pe[1], vt[1].w, fmaf(pe[0], vt[0].w, O.w * scale))));
    m = mn;
  }
  float inv = 1.f / (l + 1e-16f);
  float4 ov = make_float4(O.x * inv + sk.x, O.y * inv + sk.y,
                          O.z * inv + sk.z, O.w * inv + sk.w);
  // gate for this mini
  float ps = ov.x * wg.x + ov.y * wg.y + ov.z * wg.z + ov.w * wg.w;
  #pragma unroll
  for (int o = 1; o <= 16; o <<= 1) ps += __shfl_xor(ps, o, 64);
  __shared__ float outs[8][32][4];   // 4 KB
  __shared__ float gates[8];
  *(float4*)&outs[g][lane][0] = ov;
  if (lane == 0) gates[g] = ps + bg[0];
  __syncthreads();
  if (threadIdx.x < 32) {
    float gm = -INFINITY;
    #pragma unroll
    for (int j = 0; j < 8; ++j) gm = fmaxf(gm, gates[j]);
    float e[8], s = 0.f;
    #pragma unroll
    for (int j = 0; j < 8; ++j) { e[j] = __expf(gates[j] - gm); s += e[j]; }
    float ia = 1.f / (s + 1e-16f);
    float4 acc = make_float4(0.f, 0.f, 0.f, 0.f);
    #pragma unroll
    for (int j = 0; j < 8; ++j) {
      float a = e[j] * ia;
      float4 v = *(const float4*)&outs[j][threadIdx.x][0];
      acc.x = fmaf(a, v.x, acc.x); acc.y = fmaf(a, v.y, acc.y);
      acc.z = fmaf(a, v.z, acc.z); acc.w = fmaf(a, v.w, acc.w);
    }
    float4 o4 = b4f(*(const ushort4*)(stmt + (size_t)blockIdx.x * ED + threadIdx.x * 4));
    acc.x = (acc.x + o4.x) * 0.5f; acc.y = (acc.y + o4.y) * 0.5f;
    acc.z = (acc.z + o4.z) * 0.5f; acc.w = (acc.w + o4.w) * 0.5f;
    *(ushort4*)(out + (size_t)blockIdx.x * ED + threadIdx.x * 4) = f4b(acc);
  }
}

// ============ GCN gather (bf16): FULL WAVE per node, dual-half chunk-8 ========
__global__ void __launch_bounds__(256)
gcn_gather_b_k(const unsigned short* __restrict__ x, const float* __restrict__ dinv,
               const int* __restrict__ offs, const int* __restrict__ csr,
               const float* __restrict__ bias, unsigned short* __restrict__ out,
               const float* __restrict__ Wg, const float* __restrict__ bg,
               float* __restrict__ gateOut) {
  const int wv = threadIdx.x >> 6, lane = threadIdx.x & 63;
  const int half = lane >> 5, cl = lane & 31;
  const int n = blockIdx.x * 4 + wv;
  float di = dinv[n];
  float4 acc = make_float4(0.f, 0.f, 0.f, 0.f);
  if (half == 0) {   // self term once
    float4 xs = b4f(*(const ushort4*)(x + (size_t)n * ED + cl * 4));
    float w0 = di * di;
    acc = make_float4(w0 * xs.x, w0 * xs.y, w0 * xs.z, w0 * xs.w);
  }
  int lo = offs[n], hi = offs[n + 1];
  for (int base = lo; base < hi; base += 8) {
    int sidx[4]; bool ok[4];
    #pragma unroll
    for (int i = 0; i < 4; ++i) {
      int e = base + 2 * i + half;
      ok[i] = e < hi;
      sidx[i] = ok[i] ? csr[e] : 0;
    }
    float dw[4];
    #pragma unroll
    for (int i = 0; i < 4; ++i) dw[i] = ok[i] ? di * dinv[sidx[i]] : 0.f;
    ushort4 vr[4];
    #pragma unroll
    for (int i = 0; i < 4; ++i)
      vr[i] = *(const ushort4*)(x + (size_t)sidx[i] * ED + cl * 4);
    #pragma unroll
    for (int i = 0; i < 4; ++i) {
      float4 v = b4f(vr[i]);
      acc.x = fmaf(dw[i], v.x, acc.x); acc.y = fmaf(dw[i], v.y, acc.y);
      acc.z = fmaf(dw[i], v.z, acc.z); acc.w = fmaf(dw[i], v.w, acc.w);
    }
  }
  // merge halves
  acc.x += __shfl_xor(acc.x, 32, 64); acc.y += __shfl_xor(acc.y, 32, 64);
  acc.z += __shfl_xor(acc.z, 32, 64); acc.w += __shfl_xor(acc.w, 32, 64);
  if (bias) {
    float4 b4 = *(const float4*)(bias + cl * 4);
    acc.x += b4.x; acc.y += b4.y; acc.z += b4.z; acc.w += b4.w;
  }
  if (half == 0)
    *(ushort4*)(out + (size_t)n * ED + cl * 4) = f4b(acc);
  if (gateOut) {
    float4 wg = *(const float4*)(Wg + cl * 4);
    float ps = acc.x * wg.x + acc.y * wg.y + acc.z * wg.z + acc.w * wg.w;
    #pragma unroll
    for (int o = 1; o <= 16; o <<= 1) ps += __shfl_xor(ps, o, 64);
    if (lane == 0) gateOut[n] = ps + bg[0];
  }
}

// ======================================================================
// FUSED GEMM1+GEMM2 (verified phases B/C of R10's kernel; gather stays out):
// per 128-node block: h = relu(agg@W2+b2) -> LDS (64KB, swizzled);
// t = h@W3 -> global. A-frags from global (coalesced), grid NO/128 = 80.
// ======================================================================
__global__ void __launch_bounds__(512)
gemm12_fused_k(const unsigned short* __restrict__ Ab,   // agg [NO][128]
               const short8* __restrict__ W2f, const float* __restrict__ b2,
               const short8* __restrict__ W3f,
               unsigned short* __restrict__ tout) {     // [NO][128]
  __shared__ char buf[128 * 512];   // 64KB h-tile
  const int tid = threadIdx.x;
  const int w = tid >> 6, lane = tid & 63;
  const int r = lane & 15, qd = lane >> 4;
  const int row = w * 16 + r;
  const int n0 = blockIdx.x * 128;

  // A-frags from global (row-major [128] bf16 rows)
  short8 a1[4];
  #pragma unroll
  for (int kb = 0; kb < 4; ++kb)
    a1[kb] = *(const short8*)(Ab + (size_t)(n0 + row) * ED + kb * 32 + qd * 8);

  // ---- phase B: h = relu(A@W2 + b2) -> LDS [128][512B] (swizzled) ----
  #pragma unroll 4
  for (int cf = 0; cf < 16; ++cf) {
    f32x4 acc = (f32x4){0.f, 0.f, 0.f, 0.f};
    #pragma unroll
    for (int kb = 0; kb < 4; ++kb)
      acc = __builtin_amdgcn_mfma_f32_16x16x32_bf16(
          W2f[((size_t)(kb * 16 + cf)) * 64 + lane], a1[kb], acc, 0, 0, 0);
    const float4 bv = *(const float4*)(b2 + cf * 16 + qd * 4);
    ushort4 o;
    o.x = bf16_rne(fmaxf(acc[0] + bv.x, 0.f));
    o.y = bf16_rne(fmaxf(acc[1] + bv.y, 0.f));
    o.z = bf16_rne(fmaxf(acc[2] + bv.z, 0.f));
    o.w = bf16_rne(fmaxf(acc[3] + bv.w, 0.f));
    *(ushort4*)(buf + row * 512 + ((cf * 32 + qd * 8) ^ ((row & 7) << 4))) = o;
  }
  __syncthreads();

  // ---- phase C: t = h @ W3 -> global ----
  short8 a2[8];
  #pragma unroll
  for (int kb = 0; kb < 8; ++kb)
    a2[kb] = *(const short8*)(buf + row * 512 + ((kb * 64 + qd * 16) ^ ((row & 7) << 4)));
  #pragma unroll
  for (int cf = 0; cf < 8; ++cf) {
    f32x4 acc = (f32x4){0.f, 0.f, 0.f, 0.f};
    #pragma unroll
    for (int kb = 0; kb < 8; ++kb)
      acc = __builtin_amdgcn_mfma_f32_16x16x32_bf16(
          W3f[((size_t)(kb * 8 + cf)) * 64 + lane], a2[kb], acc, 0, 0, 0);
    ushort4 o = make_ushort4(bf16_rne(acc[0]), bf16_rne(acc[1]),
                             bf16_rne(acc[2]), bf16_rne(acc[3]));
    *(ushort4*)(tout + (size_t)(n0 + row) * ED + cf * 16 + qd * 4) = o;
  }
}

// ============ final global attention NO->BB (bf16 x) with cosine fused ====
static __device__ __forceinline__ int lower_bound_d(const int* a, int n, int key) {
  int lo = 0, hi = n;
  while (lo < hi) { int mid = (lo + hi) >> 1; if (a[mid] < key) lo = mid + 1; else hi = mid; }
  return lo;
}
__global__ void __launch_bounds__(128)
gattn_cos_k(const unsigned short* __restrict__ x, const float* __restrict__ gate,
            const int* __restrict__ seg, int Ntot,
            const float* __restrict__ hn, float* __restrict__ outp) {
  const int g = threadIdx.x >> 5, lane = threadIdx.x & 31;
  const int n = blockIdx.x * 4 + g;
  __shared__ int sh[4][2];
  if (lane == 0) {
    sh[g][0] = lower_bound_d(seg, Ntot, n);
    sh[g][1] = lower_bound_d(seg, Ntot, n + 1);
  }
  __syncthreads();
  int lo = sh[g][0], hi = sh[g][1];
  float m = -INFINITY;
  for (int j = lo; j < hi; ++j) m = fmaxf(m, gate[j]);
  float ssum = 0.f;
  for (int j = lo; j < hi; ++j) ssum += __expf(gate[j] - m);
  float inv = 1.f / (ssum + 1e-16f);
  float4 acc = make_float4(0.f, 0.f, 0.f, 0.f);
  for (int j = lo; j < hi; ++j) {
    float a = __expf(gate[j] - m) * inv;
    float4 v = b4f(*(const ushort4*)(x + (size_t)j * ED + lane * 4));
    acc.x = fmaf(a, v.x, acc.x); acc.y = fmaf(a, v.y, acc.y);
    acc.z = fmaf(a, v.z, acc.z); acc.w = fmaf(a, v.w, acc.w);
  }
  float4 hv = *(const float4*)(hn + (size_t)n * ED + lane * 4);
  float dot = acc.x * hv.x + acc.y * hv.y + acc.z * hv.z + acc.w * hv.w;
  float na  = acc.x * acc.x + acc.y * acc.y + acc.z * acc.z + acc.w * acc.w;
  float nb  = hv.x * hv.x + hv.y * hv.y + hv.z * hv.z + hv.w * hv.w;
  #pragma unroll
  for (int o = 1; o <= 16; o <<= 1) {
    dot += __shfl_xor(dot, o, 64);
    na  += __shfl_xor(na,  o, 64);
    nb  += __shfl_xor(nb,  o, 64);
  }
  if (lane == 0)
    outp[n] = dot / (fmaxf(sqrtf(na), 1e-8f) * fmaxf(sqrtf(nb), 1e-8f));
}

// ---- workspace layout (4-byte element offsets) ----
constexpr size_t OFF_HN    = 0;                                  // BB*ED
constexpr size_t OFF_STMT  = OFF_HN    + (size_t)BB * ED;        // NO*ED (bf16 in half)
constexpr size_t OFF_A     = OFF_STMT  + (size_t)NO * ED;        // NM*ED (miniE bf16 -> recycled)
constexpr size_t OFF_CT    = OFF_A     + (size_t)NM * ED;        // VV*ED floats: 2 bf16 tables
constexpr size_t OFF_QKVS  = OFF_CT    + (size_t)VV * ED;        // NM*256 floats = bf16 [NM][512]
constexpr size_t T0        = OFF_QKVS  + (size_t)NM * 256;
constexpr size_t OFF_GATE  = T0;                                 // NM (unused now)
constexpr size_t OFF_GATE2 = OFF_GATE  + (size_t)NM;             // NO
constexpr size_t OFF_DINV  = OFF_GATE2 + (size_t)NO;             // NO
constexpr size_t OFF_HISTM = OFF_DINV  + (size_t)NO;             // NM (int)
constexpr size_t OFF_HISTO = OFF_HISTM + (size_t)NM;             // NO (adjacent -> concat scan)
constexpr size_t OFF_OFFSM = OFF_HISTO + (size_t)NO;             // NM+1
constexpr size_t OFF_CURM  = OFF_OFFSM + (size_t)NM + 1;         // NM
constexpr size_t OFF_CSRM  = OFF_CURM  + (size_t)NM;             // EM
constexpr size_t OFF_OFFSO = OFF_CSRM  + (size_t)EM;             // NO+1
constexpr size_t OFF_CURO  = OFF_OFFSO + (size_t)NO + 1;         // NO
constexpr size_t OFF_CSRO  = OFF_CURO  + (size_t)NO;             // EO
constexpr size_t OFF_PART  = OFF_CSRO  + (size_t)EO;             // 512 (int)
constexpr size_t OFF_B512  = OFF_PART  + 512;                    // 512 floats (permuted bias)
constexpr size_t OFF_WFHI  = OFF_B512  + 512;                    // 65536 floats (16384 short8)
// region-A recycling after qkvs (miniE dead): all bf16
constexpr size_t OFF_MFN   = OFF_A;                              // NO*ED (bf16)
constexpr size_t OFF_AGG   = OFF_MFN   + (size_t)NO * ED;        // NO*ED (bf16)
constexpr size_t OFF_T     = OFF_AGG   + (size_t)NO * ED;        // NO*ED (bf16)
constexpr size_t OFF_FIN   = OFF_T     + (size_t)NO * ED;        // NO*ED (bf16)

extern "C" void kernel_launch(void* const* d_in, const int* in_sizes, int n_in,
                              void* d_out, int out_size, void* d_ws, size_t ws_size,
                              hipStream_t stream) {
  const int* desc_tokens = (const int*)d_in[0];
  const int* x_tokens    = (const int*)d_in[1];
  const int* mini_tokens = (const int*)d_in[2];
  const int* src         = (const int*)d_in[3];
  const int* dst         = (const int*)d_in[4];
  const int* mini_src    = (const int*)d_in[5];
  const int* mini_dst    = (const int*)d_in[6];
  const int* mini_batch  = (const int*)d_in[7];
  const int* node_batch  = (const int*)d_in[8];
  const float* desc_table  = (const float*)d_in[9];
  const float* code_table  = (const float*)d_in[10];
  const float* code_table2 = (const float*)d_in[11];
  const float* Wq = (const float*)d_in[12]; const float* bq = (const float*)d_in[13];
  const float* Wk = (const float*)d_in[14]; const float* bk = (const float*)d_in[15];
  const float* Wv = (const float*)d_in[16]; const float* bv = (const float*)d_in[17];
  const float* Wskip = (const float*)d_in[18]; const float* bskip = (const float*)d_in[19];
  const float* W2 = (const float*)d_in[20]; const float* b2 = (const float*)d_in[21];
  const float* W3 = (const float*)d_in[22]; const float* b3 = (const float*)d_in[23];
  const float* Wg = (const float*)d_in[24]; const float* bg = (const float*)d_in[25];
  (void)mini_batch;

  float* ws = (float*)d_ws;
  float* h_n   = ws + OFF_HN;
  unsigned short* stmt_b  = (unsigned short*)(ws + OFF_STMT);
  unsigned short* miniE_b = (unsigned short*)(ws + OFF_A);     // bf16 [NM][128]
  unsigned short* ctab_b  = (unsigned short*)(ws + OFF_CT);
  unsigned short* ctab2_b = ctab_b + (size_t)VV * ED;
  unsigned short* qkvs_b  = (unsigned short*)(ws + OFF_QKVS);  // bf16 [NM][512]
  float* gate2 = ws + OFF_GATE2;
  float* dinv  = ws + OFF_DINV;
  int* histm = (int*)(ws + OFF_HISTM);
  int* histo = (int*)(ws + OFF_HISTO);
  int* offsm = (int*)(ws + OFF_OFFSM);
  int* curm  = (int*)(ws + OFF_CURM);
  int* csrm  = (int*)(ws + OFF_CSRM);
  int* offso = (int*)(ws + OFF_OFFSO);
  int* curo  = (int*)(ws + OFF_CURO);
  int* csro  = (int*)(ws + OFF_CSRO);
  int* part  = (int*)(ws + OFF_PART);
  float* bias512 = ws + OFF_B512;
  short8* wfrag = (short8*)(ws + OFF_WFHI);
  unsigned short* mini_fn_b = (unsigned short*)(ws + OFF_MFN);
  unsigned short* aggb_b    = (unsigned short*)(ws + OFF_AGG);
  unsigned short* tbuf_b    = (unsigned short*)(ws + OFF_T);
  unsigned short* finalS_b  = (unsigned short*)(ws + OFF_FIN);
  float* outp    = (float*)d_out;

  // ---- conversions + hist zeroing in ONE launch ----
  ConvArgs ca;
  ca.Wq = Wq; ca.Wk = Wk; ca.Wv = Wv; ca.Ws = Wskip; ca.W2 = W2; ca.W3 = W3;
  ca.bq = bq; ca.bk = bk; ca.bv = bv; ca.bs = bskip;
  ca.frag = wfrag; ca.bias512 = bias512;
  ca.t1 = code_table;  ca.o1 = ctab_b;
  ca.t2 = code_table2; ca.o2 = ctab2_b;
  ca.hist = histm;
  conv_all_k<<<64 + TBLK + ZBLK + 1, 256, 0, stream>>>(ca);

  // ---- embeddings + edge histogram in one launch ----
  embed_all_k<<<MBLK + XBLK + BB / 8 + HBLK, 256, 0, stream>>>(
      desc_tokens, desc_table, h_n, x_tokens, ctab2_b, stmt_b,
      mini_tokens, ctab_b, miniE_b, mini_dst, dst, histm, histo);

  // ---- merged Q|KV|Skip projection + fused chunk_sum ----
  qkvs_merged_k<<<QKVSB + CSUMB, 512, 0, stream>>>(miniE_b, wfrag, bias512, qkvs_b,
                                                   histm, part);

  // ---- CSR build: scan_final (self-prefix) + scatter ----
  scan_final2_k<<<(NM + NO) / 256, 256, 0, stream>>>(histm, part, offsm, curm,
                                                     offso, curo, dinv);
  scatter2_k<<<nblk(EM + EO, 256), 256, 0, stream>>>(mini_src, mini_dst, curm, csrm,
                                                     src, dst, curo, csro);

  // ---- FUSED transformer conv + global attention mini->NO + combine ----
  attn_comb_k<<<NO, 256, 0, stream>>>(qkvs_b, offsm, csrm, Wg, bg, stmt_b, mini_fn_b);

  // ---- GCN conv 1 aggregation: agg = A_hat * mini_fn (2560-block gather) ----
  gcn_gather_b_k<<<NO / 4, 256, 0, stream>>>(mini_fn_b, dinv, offso, csro, nullptr,
                                             aggb_b, nullptr, nullptr, nullptr);

  // ---- FUSED GEMM1+GEMM2: h = relu(agg@W2+b2) in LDS; t = h@W3 ----
  gemm12_fused_k<<<NO / 128, 512, 0, stream>>>(aggb_b, wfrag + 8192, b2,
                                               wfrag + 12288, tbuf_b);

  // ---- GCN conv 2 aggregation: final = A_hat * t + b3 (+ gate2) ----
  gcn_gather_b_k<<<NO / 4, 256, 0, stream>>>(tbuf_b, dinv, offso, csro, b3, finalS_b,
                                             Wg, bg, gate2);

  // ---- global attention NO -> BB with fused cosine -> d_out [BB] ----
  gattn_cos_k<<<BB / 4, 128, 0, stream>>>(finalS_b, gate2, node_batch, NO, h_n, outp);
}

// Round 12
// 311.013 us; speedup vs baseline: 1.1316x; 1.0240x over previous
//
#include <hip/hip_runtime.h>
#include <hip/hip_bf16.h>
#include <math.h>

// Problem dims (fixed by reference)
#define BB   256      // batch
#define LDE  64       // desc tokens len
#define NO   10240    // outer nodes
#define LO   32       // x tokens len
#define NM   81920    // mini nodes
#define LM   16       // mini tokens len
#define EO   81920    // outer edges
#define EM   327680   // mini edges
#define ED   128      // embed dim E
#define HIDD 256      // hidden
#define NH   8        // heads
#define DH   16       // head dim
#define VV   10000    // vocab

static inline int nblk(long long n, int b) { return (int)((n + b - 1) / b); }

typedef __attribute__((ext_vector_type(8))) short short8;
typedef __attribute__((ext_vector_type(4))) float f32x4;

// ---- fp32 <-> bf16 (RNE) helpers ----
static __device__ __forceinline__ unsigned short bf16_rne(float f) {
  unsigned u = __float_as_uint(f);
  return (unsigned short)((u + 0x7fffu + ((u >> 16) & 1u)) >> 16);
}
static __device__ __forceinline__ float bf16_to_f(unsigned short h) {
  return __uint_as_float(((unsigned)h) << 16);
}
static __device__ __forceinline__ float4 b4f(ushort4 h) {
  return make_float4(bf16_to_f(h.x), bf16_to_f(h.y), bf16_to_f(h.z), bf16_to_f(h.w));
}
static __device__ __forceinline__ ushort4 f4b(float4 v) {
  return make_ushort4(bf16_rne(v.x), bf16_rne(v.y), bf16_rne(v.z), bf16_rne(v.w));
}

// async global->LDS, 16B/lane. LDS dest must be wave-uniform base; global src per-lane.
static __device__ __forceinline__ void gl_lds16(const void* g, void* l) {
  __builtin_amdgcn_global_load_lds(
      (const __attribute__((address_space(1))) unsigned int*)g,
      (__attribute__((address_space(3))) unsigned int*)l, 16, 0, 0);
}

// ======================================================================
// Conversion kernel
// ======================================================================
struct ConvArgs {
  const float *Wq, *Wk, *Wv, *Ws, *W2, *W3;
  const float *bq, *bk, *bv, *bs;
  short8* frag;            // 16384 octets: [0,8192) QKVS, [8192,12288) W2, [12288,16384) W3
  float* bias512;
  const float* t1; unsigned short* o1;
  const float* t2; unsigned short* o2;
  int* hist;
};
#define TBLK (2 * VV * ED / 4 / 256)      // 2500 table blocks
#define ZBLK ((NM + NO) / 256)            // 360 hist-zero blocks
__global__ void __launch_bounds__(256)
conv_all_k(ConvArgs A) {
  int b = blockIdx.x;
  if (b < 32) {
    // merged QKVS frags, chunk-major: octet g in [0,8192)
    int g = b * 256 + threadIdx.x;
    int lane = g & 63, f = g >> 6;        // f = (ch<<5)|(kb<<3)|jl
    int jl = f & 7, kb = (f >> 3) & 3, ch = f >> 5;
    int cf = ch * 8 + jl;
    int c = cf * 16 + (lane & 15);        // permuted output col, 0..511
    int k0 = kb * 32 + ((lane >> 4) << 3);
    const float* wp; int cm;
    if (c < 128)      { wp = A.Wq; cm = c; }
    else if (c < 384) { int u = c - 128, t = u & 7;
                        wp = (t < 4) ? A.Wk : A.Wv; cm = (u >> 3) * 4 + (t & 3); }
    else              { wp = A.Ws; cm = c - 384; }
    short8 h;
    #pragma unroll
    for (int j = 0; j < 8; ++j)
      h[j] = (short)bf16_rne(wp[(size_t)(k0 + j) * 128 + cm]);
    A.frag[g] = h;
  } else if (b < 64) {
    // W2/W3 frags
    int g = (b - 32) * 256 + threadIdx.x;  // 0..8191
    const float* wp; int M, dstbase, gg;
    if (g < 4096) { wp = A.W2; M = 256; dstbase = 8192;  gg = g; }
    else          { wp = A.W3; M = 128; dstbase = 12288; gg = g - 4096; }
    int lane = gg & 63, fid = gg >> 6;
    int nt = fid % (M / 16), kb = fid / (M / 16);
    int n = nt * 16 + (lane & 15);
    int k0 = kb * 32 + ((lane >> 4) << 3);
    short8 h;
    #pragma unroll
    for (int j = 0; j < 8; ++j)
      h[j] = (short)bf16_rne(wp[(size_t)(k0 + j) * M + n]);
    A.frag[dstbase + gg] = h;
  } else if (b < 64 + TBLK) {
    int q = (b - 64) * 256 + threadIdx.x;   // quad id
    const int NT = VV * ED / 4;             // 320000 per table
    if (q < NT) {
      float4 v = *(const float4*)(A.t1 + (size_t)q * 4);
      *(ushort4*)(A.o1 + (size_t)q * 4) = f4b(v);
    } else if (q < 2 * NT) {
      int q2 = q - NT;
      float4 v = *(const float4*)(A.t2 + (size_t)q2 * 4);
      *(ushort4*)(A.o2 + (size_t)q2 * 4) = f4b(v);
    }
  } else if (b < 64 + TBLK + ZBLK) {
    int i = (b - 64 - TBLK) * 256 + threadIdx.x;
    if (i < NM + NO) A.hist[i] = 0;
  } else {
    // permuted bias512
    for (int c = threadIdx.x; c < 512; c += 256) {
      float v;
      if (c < 128)      v = A.bq[c];
      else if (c < 384) { int u = c - 128, t = u & 7;
                          v = (t < 4) ? A.bk[(u >> 3) * 4 + t] : A.bv[(u >> 3) * 4 + (t & 3)]; }
      else              v = A.bs[c - 384];
      A.bias512[c] = v;
    }
  }
}

// ---- embed: fp32-table body (desc): 256 thr = 8 rows x 32 float4-lanes ----
template<int L>
static __device__ __forceinline__ void embed_body_f(const int* __restrict__ tokens,
                                                    const float* __restrict__ table,
                                                    float* __restrict__ out, int blk) {
  const int r = threadIdx.x >> 5, lane = threadIdx.x & 31;
  const int n0 = blk * 8;
  __shared__ int toks[8][L];
  for (int i = threadIdx.x; i < 8 * L; i += 256)
    toks[i / L][i % L] = tokens[(size_t)n0 * L + i];
  __syncthreads();
  float4 acc = make_float4(0.f, 0.f, 0.f, 0.f);
  int cnt = 0;
  #pragma unroll
  for (int l = 0; l < L; ++l) {
    int t = toks[r][l];
    float4 v = *(const float4*)(table + (size_t)t * ED + lane * 4);
    float msk = (t != 0) ? 1.f : 0.f;
    cnt += (t != 0);
    acc.x = fmaf(msk, v.x, acc.x); acc.y = fmaf(msk, v.y, acc.y);
    acc.z = fmaf(msk, v.z, acc.z); acc.w = fmaf(msk, v.w, acc.w);
  }
  float inv = 1.f / (float)(cnt > 0 ? cnt : 1);
  acc.x *= inv; acc.y *= inv; acc.z *= inv; acc.w *= inv;
  *(float4*)(out + (size_t)(n0 + r) * ED + lane * 4) = acc;
}

// ---- embed: bf16-table body: 256 thr = 16 rows x 16 lanes, 16B loads/stores ----
template<int L>
static __device__ __forceinline__ void embed_body16(const int* __restrict__ tokens,
                                                    const unsigned short* __restrict__ table,
                                                    unsigned short* __restrict__ out, int blk) {
  const int r = threadIdx.x >> 4, lane = threadIdx.x & 15;
  const int n0 = blk * 16;
  __shared__ int toks[16][L];
  for (int i = threadIdx.x; i < 16 * L; i += 256)
    toks[i / L][i % L] = tokens[(size_t)n0 * L + i];
  __syncthreads();
  float acc[8] = {};
  int cnt = 0;
  #pragma unroll
  for (int l = 0; l < L; ++l) {
    int t = toks[r][l];
    short8 v = *(const short8*)(table + (size_t)t * ED + lane * 8);
    float msk = (t != 0) ? 1.f : 0.f;
    cnt += (t != 0);
    #pragma unroll
    for (int j = 0; j < 8; ++j)
      acc[j] = fmaf(msk, bf16_to_f((unsigned short)v[j]), acc[j]);
  }
  float inv = 1.f / (float)(cnt > 0 ? cnt : 1);
  short8 o;
  #pragma unroll
  for (int j = 0; j < 8; ++j) o[j] = (short)bf16_rne(acc[j] * inv);
  *(short8*)(out + (size_t)(n0 + r) * ED + lane * 8) = o;
}

// embeddings + edge histogram in one launch, heavy blocks first:
// [0, NM/16) mini | [+NO/16) x | [+BB/8) desc | [+HBLK) hist
#define HBLK ((EM + EO) / 256)   // 1600
#define MBLK (NM / 16)           // 5120
#define XBLK (NO / 16)           // 640
__global__ void __launch_bounds__(256)
embed_all_k(const int* __restrict__ desc_tokens, const float* __restrict__ desc_table,
            float* __restrict__ h_n,
            const int* __restrict__ x_tokens, const unsigned short* __restrict__ ctab2,
            unsigned short* __restrict__ stmt,
            const int* __restrict__ mini_tokens, const unsigned short* __restrict__ ctab,
            unsigned short* __restrict__ miniE,
            const int* __restrict__ mini_dst, const int* __restrict__ dst,
            int* __restrict__ histm, int* __restrict__ histo) {
  int b = blockIdx.x;
  if (b < MBLK) embed_body16<LM>(mini_tokens, ctab, miniE, b);
  else if (b < MBLK + XBLK) embed_body16<LO>(x_tokens, ctab2, stmt, b - MBLK);
  else if (b < MBLK + XBLK + BB / 8)
    embed_body_f<LDE>(desc_tokens, desc_table, h_n, b - MBLK - XBLK);
  else {
    int e = (b - MBLK - XBLK - BB / 8) * 256 + threadIdx.x;   // [0, EM+EO)
    if (e < EM) atomicAdd(&histm[mini_dst[e]], 1);
    else        atomicAdd(&histo[dst[e - EM]], 1);
  }
}

// ================= CSR build: scan_final (self-prefix over raw part) + scatter ========
__global__ void __launch_bounds__(256)
scan_final2_k(const int* __restrict__ hist, const int* __restrict__ part,
              int* __restrict__ offsm, int* __restrict__ curm,
              int* __restrict__ offso, int* __restrict__ curo,
              float* __restrict__ dinv) {
  __shared__ int sd[256], red[256];
  const int b = blockIdx.x, t = threadIdx.x;
  const int i = b * 256 + t;
  const int v = hist[i];
  sd[t] = v; __syncthreads();
  for (int off = 1; off < 256; off <<= 1) {
    int a = (t >= off) ? sd[t - off] : 0;
    __syncthreads(); sd[t] += a; __syncthreads();
  }
  const int excl = sd[t] - v;
  // prefix over raw chunk sums within this segment (NM chunks | NO chunks)
  const int segBase = (b < NM / 256) ? 0 : NM / 256;
  const int myIdx = b - segBase;
  int s = 0;
  for (int k = t; k < myIdx; k += 256) s += part[segBase + k];
  red[t] = s; __syncthreads();
  for (int o = 128; o > 0; o >>= 1) { if (t < o) red[t] += red[t + o]; __syncthreads(); }
  const int off = red[0] + excl;
  if (i < NM) {
    offsm[i] = off; curm[i] = off;
    if (i == NM - 1) offsm[NM] = off + v;
  } else {
    int i2 = i - NM;
    offso[i2] = off; curo[i2] = off;
    if (i2 == NO - 1) offso[NO] = off + v;
    dinv[i2] = 1.f / sqrtf(1.f + (float)v);
  }
}
__global__ void scatter2_k(const int* __restrict__ sm, const int* __restrict__ dm,
                           int* __restrict__ cm, int* __restrict__ km,
                           const int* __restrict__ so, const int* __restrict__ dd,
                           int* __restrict__ co, int* __restrict__ ko) {
  int e = blockIdx.x * 256 + threadIdx.x;
  if (e < EM) {
    int pos = atomicAdd(&cm[dm[e]], 1);
    km[pos] = sm[e];
  } else {
    int e2 = e - EM;
    if (e2 < EO) {
      int pos = atomicAdd(&co[dd[e2]], 1);
      ko[pos] = so[e2];
    }
  }
}

// ======================================================================
// Merged QKVS GEMM v4 + fused chunk_sum (R7-proven):
//   blocks [0,640):      GEMM (XCD-swizzled)
//   blocks [640,1000):   chunk_sum over hist[NM+NO] -> part (raw sums)
// ======================================================================
#define QKVSB (NM / 128)            // 640
#define CSUMB ((NM + NO) / 256)     // 360
__global__ void __launch_bounds__(512)
qkvs_merged_k(const unsigned short* __restrict__ Ab, const short8* __restrict__ Wf,
              const float* __restrict__ bias512, unsigned short* __restrict__ out,
              const int* __restrict__ hist, int* __restrict__ part) {
  __shared__ short8 wlds[2048];          // 32 KB; doubles as per-wave 4KB epilogue / sd
  const int tid = threadIdx.x;
  if (blockIdx.x >= QKVSB) {
    // ---- chunk_sum branch ----
    int* sd = (int*)wlds;
    const int cb = blockIdx.x - QKVSB;
    const int i = cb * 256 + (tid & 255);
    if (tid < 256) sd[tid] = (i < NM + NO) ? hist[i] : 0;
    __syncthreads();
    for (int s = 128; s > 0; s >>= 1) {
      if (tid < s) sd[tid] += sd[tid + s];
      __syncthreads();
    }
    if (tid == 0) part[cb] = sd[0];
    return;
  }
  const int id = blockIdx.x;
  const int blk = (id & 7) * 80 + (id >> 3);   // XCD-bijective swizzle (640 = 8*80)
  const int n0 = blk * 128;
  const int w = tid >> 6, lane = tid & 63;
  const int r = lane & 15, qd = lane >> 4;
  const int node = n0 + w * 16 + r;
  char* myl = (char*)wlds + w * 4096;

  // A fragments for this wave's 16 nodes, full K=128
  short8 a[4];
  #pragma unroll
  for (int kb = 0; kb < 4; ++kb)
    a[kb] = *(const short8*)(Ab + (size_t)node * ED + kb * 32 + qd * 8);

  for (int ch = 0; ch < 4; ++ch) {
    // ---- stage chunk weights into own 4KB region: 4 x (64 lanes x 16B) ----
    {
      const char* gs = (const char*)Wf + (size_t)ch * 32768
                     + (size_t)(w * 4) * 1024 + (size_t)lane * 16;
      char* ls = (char*)wlds + (w * 4) * 1024;   // wave-uniform == own region
      #pragma unroll
      for (int t = 0; t < 4; ++t)
        gl_lds16(gs + t * 1024, ls + t * 1024);
    }
    __syncthreads();   // chunk resident

    f32x4 acc[8];
    #pragma unroll
    for (int jl = 0; jl < 8; ++jl) acc[jl] = (f32x4){0.f, 0.f, 0.f, 0.f};
    #pragma unroll
    for (int kb = 0; kb < 4; ++kb)
      #pragma unroll
      for (int jl = 0; jl < 8; ++jl) {
        short8 wf = *(const short8*)((const char*)wlds
                      + ((size_t)((kb << 3) | jl) * 64 + lane) * 16);
        acc[jl] = __builtin_amdgcn_mfma_f32_16x16x32_bf16(wf, a[kb], acc[jl], 0, 0, 0);
      }
    __syncthreads();   // all waves done reading weights -> LDS reusable

    // epilogue into own 4KB (16 rows x 256B, XOR-swizzled bits 5..7)
    #pragma unroll
    for (int jl = 0; jl < 8; ++jl) {
      const int cf = ch * 8 + jl;
      const float4 bv = *(const float4*)(bias512 + cf * 16 + qd * 4);
      ushort4 o;
      o.x = bf16_rne(acc[jl][0] + bv.x);
      o.y = bf16_rne(acc[jl][1] + bv.y);
      o.z = bf16_rne(acc[jl][2] + bv.z);
      o.w = bf16_rne(acc[jl][3] + bv.w);
      *(ushort4*)(myl + r * 256 + ((jl * 32) ^ ((r & 7) << 5)) + qd * 8) = o;
    }
    // drain: 16 rows x 256B -> global, 16B/lane, 4 rounds of 4 rows
    #pragma unroll
    for (int t = 0; t < 4; ++t) {
      const int rr = t * 4 + qd;
      short8 v = *(const short8*)(myl + rr * 256 + (((lane & 15) * 16) ^ ((rr & 7) << 5)));
      *(short8*)(out + (size_t)(n0 + w * 16 + rr) * 512 + ch * 128 + (lane & 15) * 8) = v;
    }
    __syncthreads();   // drains done before next stage overwrites
  }
}

// ========== generic single-term bf16 GEMM: bf16 A (row-major) x frag-W -> bf16 C ======
template<bool RELU>
__global__ void __launch_bounds__(512)
mgemm_b_k(const unsigned short* __restrict__ Ab, const short8* __restrict__ Bh,
          const float* __restrict__ bias, unsigned short* __restrict__ C,
          int K, int M) {
  const int bn0 = blockIdx.x * 128;
  const int n0 = blockIdx.y * 128;
  const int tid = threadIdx.x;
  const int w = tid >> 6, lane = tid & 63;
  const int wm = (w & 3) * 2, wn = (w >> 2) * 4;
  const int r = lane & 15, qd = lane >> 4;
  const int NTm = M / 16;
  f32x4 acc[2][4];
  #pragma unroll
  for (int i = 0; i < 2; ++i)
    #pragma unroll
    for (int j = 0; j < 4; ++j) acc[i][j] = (f32x4){0.f, 0.f, 0.f, 0.f};
  const int kbn = K / 32;
  for (int kb = 0; kb < kbn; ++kb) {
    short8 bh[4];
    #pragma unroll
    for (int j = 0; j < 4; ++j)
      bh[j] = Bh[((size_t)kb * NTm + (bn0 >> 4) + wn + j) * 64 + lane];
    short8 a[2];
    #pragma unroll
    for (int i = 0; i < 2; ++i)
      a[i] = *(const short8*)(Ab + (size_t)(n0 + (wm + i) * 16 + r) * K + kb * 32 + qd * 8);
    #pragma unroll
    for (int i = 0; i < 2; ++i)
      #pragma unroll
      for (int j = 0; j < 4; ++j)
        acc[i][j] = __builtin_amdgcn_mfma_f32_16x16x32_bf16(bh[j], a[i], acc[i][j], 0, 0, 0);
  }
  #pragma unroll
  for (int i = 0; i < 2; ++i)
    #pragma unroll
    for (int j = 0; j < 4; ++j) {
      const int node = n0 + (wm + i) * 16 + r;
      const int colb = bn0 + (wn + j) * 16 + qd * 4;
      float4 bv = bias ? *(const float4*)(bias + colb) : make_float4(0.f, 0.f, 0.f, 0.f);
      float v0 = acc[i][j][0] + bv.x;
      float v1 = acc[i][j][1] + bv.y;
      float v2 = acc[i][j][2] + bv.z;
      float v3 = acc[i][j][3] + bv.w;
      if (RELU) {
        v0 = fmaxf(v0, 0.f); v1 = fmaxf(v1, 0.f);
        v2 = fmaxf(v2, 0.f); v3 = fmaxf(v3, 0.f);
      }
      ushort4 o = make_ushort4(bf16_rne(v0), bf16_rne(v1), bf16_rne(v2), bf16_rne(v3));
      *(ushort4*)(C + (size_t)node * M + colb) = o;
    }
}

// ======================================================================
// FUSED TransformerConv + global-attention-combine (R9-proven).
// ======================================================================
__global__ void __launch_bounds__(256)
attn_comb_k(const unsigned short* __restrict__ buf,
            const int* __restrict__ offs, const int* __restrict__ csr,
            const float* __restrict__ Wg, const float* __restrict__ bg,
            const unsigned short* __restrict__ stmt, unsigned short* __restrict__ out) {
  const int g = threadIdx.x >> 5, lane = threadIdx.x & 31;
  const int n = blockIdx.x * 8 + g;          // mini node
  float4 q = b4f(*(const ushort4*)(buf + (size_t)n * 512 + lane * 4));
  float4 sk = b4f(*(const ushort4*)(buf + (size_t)n * 512 + 384 + lane * 4));
  float4 wg = *(const float4*)(Wg + lane * 4);
  int lo = offs[n], hi = offs[n + 1];
  float4 O = make_float4(0.f, 0.f, 0.f, 0.f);
  float m = -INFINITY, l = 0.f;
  for (int base = lo; base < hi; base += 4) {
    int rem = hi - base;                      // >= 1
    int sidx[4];
    #pragma unroll
    for (int i = 0; i < 4; ++i) sidx[i] = (i < rem) ? csr[base + i] : 0;
    short8 kvr[4];
    #pragma unroll
    for (int i = 0; i < 4; ++i)
      kvr[i] = *(const short8*)(buf + (size_t)sidx[i] * 512 + 128 + lane * 8);
    float sc[4]; float4 vt[4];
    #pragma unroll
    for (int i = 0; i < 4; ++i) {
      float4 kt = make_float4(bf16_to_f((unsigned short)kvr[i][0]),
                              bf16_to_f((unsigned short)kvr[i][1]),
                              bf16_to_f((unsigned short)kvr[i][2]),
                              bf16_to_f((unsigned short)kvr[i][3]));
      vt[i] = make_float4(bf16_to_f((unsigned short)kvr[i][4]),
                          bf16_to_f((unsigned short)kvr[i][5]),
                          bf16_to_f((unsigned short)kvr[i][6]),
                          bf16_to_f((unsigned short)kvr[i][7]));
      float p = q.x * kt.x + q.y * kt.y + q.z * kt.z + q.w * kt.w;
      p += __shfl_xor(p, 1, 64);
      p += __shfl_xor(p, 2, 64);
      sc[i] = (i < rem) ? p * 0.25f : -INFINITY;   // 1/sqrt(Dh); pad = no-op
    }
    float mt = fmaxf(fmaxf(sc[0], sc[1]), fmaxf(sc[2], sc[3]));
    float mn = fmaxf(m, mt);                        // finite (rem>=1)
    float scale = __expf(m - mn);                   // first chunk: exp(-inf)=0
    float pe[4];
    #pragma unroll
    for (int i = 0; i < 4; ++i) pe[i] = __expf(sc[i] - mn);   // pads -> 0
    l = l * scale + ((pe[0] + pe[1]) + (pe[2] + pe[3]));
    O.x = fmaf(pe[3], vt[3].x, fmaf(pe[2], vt[2].x, fmaf(pe[1], vt[1].x, fmaf(pe[0], vt[0].x, O.x * scale))));
    O.y = fmaf(pe[3], vt[3].y, fmaf(pe[2], vt[2].y, fmaf(pe[1], vt[1].y, fmaf(pe[0], vt[0].y, O.y * scale))));
    O.z = fmaf(pe[3], vt[3].z, fmaf(pe[2], vt[2].z, fmaf(pe[1], vt[1].z, fmaf(pe[0], vt[0].z, O.z * scale))));
    O.w = fmaf(pe[3], vt[3].w, fmaf(pe[2], vt[2].w, fmaf(pe[1], vt[1].w, fmaf(pe[0], vt[0].w, O.w * scale))));
    m = mn;
  }
  float inv = 1.f / (l + 1e-16f);
  float4 ov = make_float4(O.x * inv + sk.x, O.y * inv + sk.y,
                          O.z * inv + sk.z, O.w * inv + sk.w);
  // gate for this mini
  float ps = ov.x * wg.x + ov.y * wg.y + ov.z * wg.z + ov.w * wg.w;
  #pragma unroll
  for (int o = 1; o <= 16; o <<= 1) ps += __shfl_xor(ps, o, 64);
  __shared__ float outs[8][32][4];   // 4 KB
  __shared__ float gates[8];
  *(float4*)&outs[g][lane][0] = ov;
  if (lane == 0) gates[g] = ps + bg[0];
  __syncthreads();
  if (threadIdx.x < 32) {
    float gm = -INFINITY;
    #pragma unroll
    for (int j = 0; j < 8; ++j) gm = fmaxf(gm, gates[j]);
    float e[8], s = 0.f;
    #pragma unroll
    for (int j = 0; j < 8; ++j) { e[j] = __expf(gates[j] - gm); s += e[j]; }
    float ia = 1.f / (s + 1e-16f);
    float4 acc = make_float4(0.f, 0.f, 0.f, 0.f);
    #pragma unroll
    for (int j = 0; j < 8; ++j) {
      float a = e[j] * ia;
      float4 v = *(const float4*)&outs[j][threadIdx.x][0];
      acc.x = fmaf(a, v.x, acc.x); acc.y = fmaf(a, v.y, acc.y);
      acc.z = fmaf(a, v.z, acc.z); acc.w = fmaf(a, v.w, acc.w);
    }
    float4 o4 = b4f(*(const ushort4*)(stmt + (size_t)blockIdx.x * ED + threadIdx.x * 4));
    acc.x = (acc.x + o4.x) * 0.5f; acc.y = (acc.y + o4.y) * 0.5f;
    acc.z = (acc.z + o4.z) * 0.5f; acc.w = (acc.w + o4.w) * 0.5f;
    *(ushort4*)(out + (size_t)blockIdx.x * ED + threadIdx.x * 4) = f4b(acc);
  }
}

// ============ GCN gather (bf16): FULL WAVE per node, dual-half chunk-8 ========
__global__ void __launch_bounds__(256)
gcn_gather_b_k(const unsigned short* __restrict__ x, const float* __restrict__ dinv,
               const int* __restrict__ offs, const int* __restrict__ csr,
               const float* __restrict__ bias, unsigned short* __restrict__ out,
               const float* __restrict__ Wg, const float* __restrict__ bg,
               float* __restrict__ gateOut) {
  const int wv = threadIdx.x >> 6, lane = threadIdx.x & 63;
  const int half = lane >> 5, cl = lane & 31;
  const int n = blockIdx.x * 4 + wv;
  float di = dinv[n];
  float4 acc = make_float4(0.f, 0.f, 0.f, 0.f);
  if (half == 0) {   // self term once
    float4 xs = b4f(*(const ushort4*)(x + (size_t)n * ED + cl * 4));
    float w0 = di * di;
    acc = make_float4(w0 * xs.x, w0 * xs.y, w0 * xs.z, w0 * xs.w);
  }
  int lo = offs[n], hi = offs[n + 1];
  for (int base = lo; base < hi; base += 8) {
    int sidx[4]; bool ok[4];
    #pragma unroll
    for (int i = 0; i < 4; ++i) {
      int e = base + 2 * i + half;
      ok[i] = e < hi;
      sidx[i] = ok[i] ? csr[e] : 0;
    }
    float dw[4];
    #pragma unroll
    for (int i = 0; i < 4; ++i) dw[i] = ok[i] ? di * dinv[sidx[i]] : 0.f;
    ushort4 vr[4];
    #pragma unroll
    for (int i = 0; i < 4; ++i)
      vr[i] = *(const ushort4*)(x + (size_t)sidx[i] * ED + cl * 4);
    #pragma unroll
    for (int i = 0; i < 4; ++i) {
      float4 v = b4f(vr[i]);
      acc.x = fmaf(dw[i], v.x, acc.x); acc.y = fmaf(dw[i], v.y, acc.y);
      acc.z = fmaf(dw[i], v.z, acc.z); acc.w = fmaf(dw[i], v.w, acc.w);
    }
  }
  // merge halves
  acc.x += __shfl_xor(acc.x, 32, 64); acc.y += __shfl_xor(acc.y, 32, 64);
  acc.z += __shfl_xor(acc.z, 32, 64); acc.w += __shfl_xor(acc.w, 32, 64);
  if (bias) {
    float4 b4 = *(const float4*)(bias + cl * 4);
    acc.x += b4.x; acc.y += b4.y; acc.z += b4.z; acc.w += b4.w;
  }
  if (half == 0)
    *(ushort4*)(out + (size_t)n * ED + cl * 4) = f4b(acc);
  if (gateOut) {
    float4 wg = *(const float4*)(Wg + cl * 4);
    float ps = acc.x * wg.x + acc.y * wg.y + acc.z * wg.z + acc.w * wg.w;
    #pragma unroll
    for (int o = 1; o <= 16; o <<= 1) ps += __shfl_xor(ps, o, 64);
    if (lane == 0) gateOut[n] = ps + bg[0];
  }
}

// ============ final global attention NO->BB (bf16 x) with cosine fused ====
static __device__ __forceinline__ int lower_bound_d(const int* a, int n, int key) {
  int lo = 0, hi = n;
  while (lo < hi) { int mid = (lo + hi) >> 1; if (a[mid] < key) lo = mid + 1; else hi = mid; }
  return lo;
}
__global__ void __launch_bounds__(128)
gattn_cos_k(const unsigned short* __restrict__ x, const float* __restrict__ gate,
            const int* __restrict__ seg, int Ntot,
            const float* __restrict__ hn, float* __restrict__ outp) {
  const int g = threadIdx.x >> 5, lane = threadIdx.x & 31;
  const int n = blockIdx.x * 4 + g;
  __shared__ int sh[4][2];
  if (lane == 0) {
    sh[g][0] = lower_bound_d(seg, Ntot, n);
    sh[g][1] = lower_bound_d(seg, Ntot, n + 1);
  }
  __syncthreads();
  int lo = sh[g][0], hi = sh[g][1];
  float m = -INFINITY;
  for (int j = lo; j < hi; ++j) m = fmaxf(m, gate[j]);
  float ssum = 0.f;
  for (int j = lo; j < hi; ++j) ssum += __expf(gate[j] - m);
  float inv = 1.f / (ssum + 1e-16f);
  float4 acc = make_float4(0.f, 0.f, 0.f, 0.f);
  for (int j = lo; j < hi; ++j) {
    float a = __expf(gate[j] - m) * inv;
    float4 v = b4f(*(const ushort4*)(x + (size_t)j * ED + lane * 4));
    acc.x = fmaf(a, v.x, acc.x); acc.y = fmaf(a, v.y, acc.y);
    acc.z = fmaf(a, v.z, acc.z); acc.w = fmaf(a, v.w, acc.w);
  }
  float4 hv = *(const float4*)(hn + (size_t)n * ED + lane * 4);
  float dot = acc.x * hv.x + acc.y * hv.y + acc.z * hv.z + acc.w * hv.w;
  float na  = acc.x * acc.x + acc.y * acc.y + acc.z * acc.z + acc.w * acc.w;
  float nb  = hv.x * hv.x + hv.y * hv.y + hv.z * hv.z + hv.w * hv.w;
  #pragma unroll
  for (int o = 1; o <= 16; o <<= 1) {
    dot += __shfl_xor(dot, o, 64);
    na  += __shfl_xor(na,  o, 64);
    nb  += __shfl_xor(nb,  o, 64);
  }
  if (lane == 0)
    outp[n] = dot / (fmaxf(sqrtf(na), 1e-8f) * fmaxf(sqrtf(nb), 1e-8f));
}

// ---- workspace layout (4-byte element offsets) ----
constexpr size_t OFF_HN    = 0;                                  // BB*ED
constexpr size_t OFF_STMT  = OFF_HN    + (size_t)BB * ED;        // NO*ED (bf16 in half)
constexpr size_t OFF_A     = OFF_STMT  + (size_t)NO * ED;        // NM*ED (miniE bf16 -> recycled)
constexpr size_t OFF_CT    = OFF_A     + (size_t)NM * ED;        // VV*ED floats: 2 bf16 tables
constexpr size_t OFF_QKVS  = OFF_CT    + (size_t)VV * ED;        // NM*256 floats = bf16 [NM][512]
constexpr size_t T0        = OFF_QKVS  + (size_t)NM * 256;
constexpr size_t OFF_GATE  = T0;                                 // NM (unused now)
constexpr size_t OFF_GATE2 = OFF_GATE  + (size_t)NM;             // NO
constexpr size_t OFF_DINV  = OFF_GATE2 + (size_t)NO;             // NO
constexpr size_t OFF_HISTM = OFF_DINV  + (size_t)NO;             // NM (int)
constexpr size_t OFF_HISTO = OFF_HISTM + (size_t)NM;             // NO (adjacent -> concat scan)
constexpr size_t OFF_OFFSM = OFF_HISTO + (size_t)NO;             // NM+1
constexpr size_t OFF_CURM  = OFF_OFFSM + (size_t)NM + 1;         // NM
constexpr size_t OFF_CSRM  = OFF_CURM  + (size_t)NM;             // EM
constexpr size_t OFF_OFFSO = OFF_CSRM  + (size_t)EM;             // NO+1
constexpr size_t OFF_CURO  = OFF_OFFSO + (size_t)NO + 1;         // NO
constexpr size_t OFF_CSRO  = OFF_CURO  + (size_t)NO;             // EO
constexpr size_t OFF_PART  = OFF_CSRO  + (size_t)EO;             // 512 (int)
constexpr size_t OFF_B512  = OFF_PART  + 512;                    // 512 floats (permuted bias)
constexpr size_t OFF_WFHI  = OFF_B512  + 512;                    // 65536 floats (16384 short8)
// region-A recycling after qkvs (miniE dead): all bf16
constexpr size_t OFF_MFN   = OFF_A;                              // NO*ED (bf16)
constexpr size_t OFF_AGG   = OFF_MFN   + (size_t)NO * ED;        // NO*ED (bf16)
constexpr size_t OFF_H     = OFF_AGG   + (size_t)NO * ED;        // NO*HIDD (bf16)
constexpr size_t OFF_T     = OFF_H     + (size_t)NO * HIDD;      // NO*ED (bf16)
constexpr size_t OFF_FIN   = OFF_T     + (size_t)NO * ED;        // NO*ED (bf16)

extern "C" void kernel_launch(void* const* d_in, const int* in_sizes, int n_in,
                              void* d_out, int out_size, void* d_ws, size_t ws_size,
                              hipStream_t stream) {
  const int* desc_tokens = (const int*)d_in[0];
  const int* x_tokens    = (const int*)d_in[1];
  const int* mini_tokens = (const int*)d_in[2];
  const int* src         = (const int*)d_in[3];
  const int* dst         = (const int*)d_in[4];
  const int* mini_src    = (const int*)d_in[5];
  const int* mini_dst    = (const int*)d_in[6];
  const int* mini_batch  = (const int*)d_in[7];
  const int* node_batch  = (const int*)d_in[8];
  const float* desc_table  = (const float*)d_in[9];
  const float* code_table  = (const float*)d_in[10];
  const float* code_table2 = (const float*)d_in[11];
  const float* Wq = (const float*)d_in[12]; const float* bq = (const float*)d_in[13];
  const float* Wk = (const float*)d_in[14]; const float* bk = (const float*)d_in[15];
  const float* Wv = (const float*)d_in[16]; const float* bv = (const float*)d_in[17];
  const float* Wskip = (const float*)d_in[18]; const float* bskip = (const float*)d_in[19];
  const float* W2 = (const float*)d_in[20]; const float* b2 = (const float*)d_in[21];
  const float* W3 = (const float*)d_in[22]; const float* b3 = (const float*)d_in[23];
  const float* Wg = (const float*)d_in[24]; const float* bg = (const float*)d_in[25];
  (void)mini_batch;

  float* ws = (float*)d_ws;
  float* h_n   = ws + OFF_HN;
  unsigned short* stmt_b  = (unsigned short*)(ws + OFF_STMT);
  unsigned short* miniE_b = (unsigned short*)(ws + OFF_A);     // bf16 [NM][128]
  unsigned short* ctab_b  = (unsigned short*)(ws + OFF_CT);
  unsigned short* ctab2_b = ctab_b + (size_t)VV * ED;
  unsigned short* qkvs_b  = (unsigned short*)(ws + OFF_QKVS);  // bf16 [NM][512]
  float* gate2 = ws + OFF_GATE2;
  float* dinv  = ws + OFF_DINV;
  int* histm = (int*)(ws + OFF_HISTM);
  int* histo = (int*)(ws + OFF_HISTO);
  int* offsm = (int*)(ws + OFF_OFFSM);
  int* curm  = (int*)(ws + OFF_CURM);
  int* csrm  = (int*)(ws + OFF_CSRM);
  int* offso = (int*)(ws + OFF_OFFSO);
  int* curo  = (int*)(ws + OFF_CURO);
  int* csro  = (int*)(ws + OFF_CSRO);
  int* part  = (int*)(ws + OFF_PART);
  float* bias512 = ws + OFF_B512;
  short8* wfrag = (short8*)(ws + OFF_WFHI);
  unsigned short* mini_fn_b = (unsigned short*)(ws + OFF_MFN);
  unsigned short* aggb_b    = (unsigned short*)(ws + OFF_AGG);
  unsigned short* hbuf_b    = (unsigned short*)(ws + OFF_H);
  unsigned short* tbuf_b    = (unsigned short*)(ws + OFF_T);
  unsigned short* finalS_b  = (unsigned short*)(ws + OFF_FIN);
  float* outp    = (float*)d_out;

  // ---- conversions + hist zeroing in ONE launch ----
  ConvArgs ca;
  ca.Wq = Wq; ca.Wk = Wk; ca.Wv = Wv; ca.Ws = Wskip; ca.W2 = W2; ca.W3 = W3;
  ca.bq = bq; ca.bk = bk; ca.bv = bv; ca.bs = bskip;
  ca.frag = wfrag; ca.bias512 = bias512;
  ca.t1 = code_table;  ca.o1 = ctab_b;
  ca.t2 = code_table2; ca.o2 = ctab2_b;
  ca.hist = histm;
  conv_all_k<<<64 + TBLK + ZBLK + 1, 256, 0, stream>>>(ca);

  // ---- embeddings + edge histogram in one launch ----
  embed_all_k<<<MBLK + XBLK + BB / 8 + HBLK, 256, 0, stream>>>(
      desc_tokens, desc_table, h_n, x_tokens, ctab2_b, stmt_b,
      mini_tokens, ctab_b, miniE_b, mini_dst, dst, histm, histo);

  // ---- merged Q|KV|Skip projection + fused chunk_sum ----
  qkvs_merged_k<<<QKVSB + CSUMB, 512, 0, stream>>>(miniE_b, wfrag, bias512, qkvs_b,
                                                   histm, part);

  // ---- CSR build: scan_final (self-prefix) + scatter ----
  scan_final2_k<<<(NM + NO) / 256, 256, 0, stream>>>(histm, part, offsm, curm,
                                                     offso, curo, dinv);
  scatter2_k<<<nblk(EM + EO, 256), 256, 0, stream>>>(mini_src, mini_dst, curm, csrm,
                                                     src, dst, curo, csro);

  // ---- FUSED transformer conv + global attention mini->NO + combine ----
  attn_comb_k<<<NO, 256, 0, stream>>>(qkvs_b, offsm, csrm, Wg, bg, stmt_b, mini_fn_b);

  // ---- GCN conv 1: agg = A_hat * mini_fn ; h = relu(agg @ W2 + b2) ----
  gcn_gather_b_k<<<NO / 4, 256, 0, stream>>>(mini_fn_b, dinv, offso, csro, nullptr,
                                             aggb_b, nullptr, nullptr, nullptr);
  { dim3 g(HIDD / 128, NO / 128);
    mgemm_b_k<true><<<g, 512, 0, stream>>>(aggb_b, wfrag + 8192, b2, hbuf_b, ED, HIDD); }

  // ---- GCN conv 2: t = h @ W3 ; final = A_hat * t + b3 (+ gate2) ----
  { dim3 g(1, NO / 128);
    mgemm_b_k<false><<<g, 512, 0, stream>>>(hbuf_b, wfrag + 12288, nullptr, tbuf_b, HIDD, ED); }
  gcn_gather_b_k<<<NO / 4, 256, 0, stream>>>(tbuf_b, dinv, offso, csro, b3, finalS_b,
                                             Wg, bg, gate2);

  // ---- global attention NO -> BB with fused cosine -> d_out [BB] ----
  gattn_cos_k<<<BB / 4, 128, 0, stream>>>(finalS_b, gate2, node_batch, NO, h_n, outp);
}